// Round 5
// baseline (2105.977 us; speedup 1.0000x reference)
//
#include <hip/hip_runtime.h>
#include <hip/hip_bf16.h>
#include <math.h>

#define NN 30000
#define NE 480000
#define HD 128
#define NLAYER 4
#define NGR 32
#define NOUT 12
#define EPS_BN 1e-5f
#define EPS_STD 1e-5f
#define AVG_LOG 1.3821454785305053f

typedef unsigned short ushort_t;

__device__ __forceinline__ float bfu(ushort_t u){
  union { unsigned int ui; float f; } c; c.ui = ((unsigned int)u) << 16; return c.f;
}

// ---------------- runtime dtype detection ----------------
// Reads first 1024 elements of x under both interpretations; the correct one
// has ~all magnitudes in a sane band for N(0,1) data.
__device__ __forceinline__ int plausible(unsigned int bits32){
  unsigned int e = (bits32 >> 23) & 0xFF;
  if(e == 0xFF) return 0;                 // inf/nan
  if(bits32 == 0 || bits32 == 0x80000000u) return 1;  // exact zero
  // |v| in [2^-34, 2^14] ~ [6e-11, 1.6e4]
  return (e >= 93 && e <= 140) ? 1 : 0;
}

__global__ void k_detect(const ushort_t* __restrict__ xr, int* __restrict__ flag){
  __shared__ int cnt[2];
  if(threadIdx.x < 2) cnt[threadIdx.x] = 0;
  __syncthreads();
  const unsigned int* xf = (const unsigned int*)xr;
  int gf = 0, gb = 0;
  for(int i = threadIdx.x; i < 1024; i += 256){
    gf += plausible(xf[i]);                       // fp32 interpretation
    gb += plausible(((unsigned int)xr[i]) << 16); // bf16 interpretation
  }
  atomicAdd(&cnt[0], gf);
  atomicAdd(&cnt[1], gb);
  __syncthreads();
  if(threadIdx.x == 0) *flag = (cnt[1] >= cnt[0]) ? 1 : 0;  // 1 = bf16
}

// ---------------- batched conversion (bf16 or fp32 source) ----------------
#define NJOBS 19
struct CvtJob { const void* s; float* d; int n; };
struct CvtArgs { CvtJob j[NJOBS]; const int* flag; };

__global__ void k_cvt(CvtArgs a){
  int ji = blockIdx.y;
  const int isbf = *a.flag;
  float* d = a.j[ji].d;
  int n = a.j[ji].n;
  if(isbf){
    const ushort_t* s = (const ushort_t*)a.j[ji].s;
    for(int i = blockIdx.x*256 + threadIdx.x; i < n; i += gridDim.x*256)
      d[i] = bfu(s[i]);
  } else {
    const float* s = (const float*)a.j[ji].s;
    for(int i = blockIdx.x*256 + threadIdx.x; i < n; i += gridDim.x*256)
      d[i] = s[i];
  }
}

// ---------------- CSR build ----------------
__global__ void k_deg(const int* __restrict__ dst, int* __restrict__ deg){
  int i = blockIdx.x*256 + threadIdx.x;
  if(i < NE){
    unsigned d = (unsigned)dst[i];
    if(d < NN) atomicAdd(&deg[d], 1);
  }
}

__global__ void k_scan(const int* __restrict__ deg, int* __restrict__ rp){
  __shared__ int sm[1024];
  __shared__ int carry;
  if(threadIdx.x==0){ carry=0; rp[0]=0; }
  __syncthreads();
  for(int base=0; base<NN; base+=1024){
    int i = base + threadIdx.x;
    int v = (i<NN) ? deg[i] : 0;
    sm[threadIdx.x] = v;
    __syncthreads();
    for(int off=1; off<1024; off<<=1){
      int t = 0;
      if(threadIdx.x >= off) t = sm[threadIdx.x-off];
      __syncthreads();
      if(threadIdx.x >= off) sm[threadIdx.x] += t;
      __syncthreads();
    }
    if(i<NN) rp[i+1] = sm[threadIdx.x] + carry;
    __syncthreads();
    if(threadIdx.x==0) carry += sm[1023];
    __syncthreads();
  }
}

__global__ void k_scatter(const int* __restrict__ src, const int* __restrict__ dst,
                          const int* __restrict__ rp, int* __restrict__ fill,
                          int* __restrict__ src_csr, int* __restrict__ eix_csr){
  int i = blockIdx.x*256 + threadIdx.x;
  if(i >= NE) return;
  unsigned d = (unsigned)dst[i];
  unsigned s = (unsigned)src[i];
  if(d >= NN || s >= NN) return;
  int pos = rp[d] + atomicAdd(&fill[d], 1);
  src_csr[pos] = (int)s;
  eix_csr[pos] = i;
}

// gather edge_attr into CSR order as fp32, dtype-aware
__global__ void k_gather_ea(const int* __restrict__ eix, const void* __restrict__ ea,
                            float* __restrict__ out, const int* __restrict__ flag){
  int j = blockIdx.x*128 + threadIdx.x;
  if(j >= NE) return;
  int i = eix[j];
  float* d = out + (size_t)j*16;
  if(*flag){
    const ushort_t* s = (const ushort_t*)ea + (size_t)i*16;
    #pragma unroll
    for(int k=0;k<16;k++) d[k] = bfu(s[k]);
  } else {
    const float* s = (const float*)ea + (size_t)i*16;
    #pragma unroll
    for(int k=0;k<16;k++) d[k] = s[k];
  }
}

// ---------------- fused weight prep ----------------
// Kf[l] : rows 0..15 = embW @ encW_l @ P3_l ; row 16 = bias row
__global__ void k_prep_K(const float* __restrict__ embW, const float* __restrict__ embB,
                         const float* __restrict__ encW, const float* __restrict__ encB,
                         const float* __restrict__ preW, const float* __restrict__ preB,
                         float* __restrict__ Kf){
  int l = blockIdx.x, c = threadIdx.x;
  const float* eW = encW + (size_t)l*128*128;
  const float* P3 = preW + (size_t)l*384*128 + 256*128;
  __shared__ float tmp[17][128];
  for(int r=0;r<16;r++){
    float a = 0.f;
    for(int k=0;k<128;k++) a += embW[r*128+k]*eW[k*128+c];
    tmp[r][c] = a;
  }
  {
    float a = encB[l*128+c];
    for(int k=0;k<128;k++) a += embB[k]*eW[k*128+c];
    tmp[16][c] = a;
  }
  __syncthreads();
  float* o = Kf + (size_t)l*17*128;
  for(int r=0;r<16;r++){
    float a = 0.f;
    for(int k=0;k<128;k++) a += tmp[r][k]*P3[k*128+c];
    o[r*128+c] = a;
  }
  {
    float a = preB[l*128+c];
    for(int k=0;k<128;k++) a += tmp[16][k]*P3[k*128+c];
    o[16*128+c] = a;
  }
}

// Wcat[l] : [512,384] from post_W rows 128..1664 (blocks of 512 per amp-scalar)
__global__ void k_prep_Wcat(const float* __restrict__ postW, float* __restrict__ Wcat){
  int i = blockIdx.x*256 + threadIdx.x;
  if(i >= 4*512*384) return;
  int l = i/(512*384); int rem = i%(512*384);
  int k = rem/384; int c = rem%384;
  int blk = c>>7; int col = c&127;
  Wcat[i] = postW[(size_t)l*1664*128 + (size_t)(128 + blk*512 + k)*128 + col];
}

// ---------------- generic fp32 tiled GEMM, 64x64 tile, 4x4 micro ----------------
template<int EPI>
__launch_bounds__(256)
__global__ void k_gemm(const float* __restrict__ A, const float* __restrict__ B,
                       float* __restrict__ C, int M, int K, int ldb, int ldc,
                       const float* __restrict__ bias,
                       const float* __restrict__ Tm,
                       const float* __restrict__ ampv,
                       const float* __restrict__ invv,
                       float* __restrict__ bnsum, float* __restrict__ bnsq){
  __shared__ float As[16][64];
  __shared__ float Bs[16][64];
  const int tid = threadIdx.x;
  const int tx = tid & 15, ty = tid >> 4;
  const int m0 = blockIdx.x*64, n0 = blockIdx.y*64;
  const int am = tid >> 2, ak = (tid & 3)*4;
  const int brr = tid >> 4, bcc = (tid & 15)*4;
  float acc[4][4] = {};
  for(int k0=0; k0<K; k0+=16){
    float4 av = make_float4(0.f,0.f,0.f,0.f);
    int ar = m0 + am;
    if(ar < M) av = *(const float4*)(A + (size_t)ar*K + k0 + ak);
    float4 bv = *(const float4*)(B + (size_t)(k0+brr)*ldb + n0 + bcc);
    __syncthreads();
    As[ak+0][am]=av.x; As[ak+1][am]=av.y; As[ak+2][am]=av.z; As[ak+3][am]=av.w;
    *(float4*)&Bs[brr][bcc] = bv;
    __syncthreads();
    #pragma unroll
    for(int kk=0; kk<16; kk++){
      float4 a4 = *(const float4*)&As[kk][ty*4];
      float4 b4 = *(const float4*)&Bs[kk][tx*4];
      float aa[4] = {a4.x,a4.y,a4.z,a4.w};
      float bb[4] = {b4.x,b4.y,b4.z,b4.w};
      #pragma unroll
      for(int i=0;i<4;i++)
        #pragma unroll
        for(int j=0;j<4;j++)
          acc[i][j] += aa[i]*bb[j];
    }
  }
  const int col0 = n0 + tx*4;
  float s[4] = {0,0,0,0}, q[4] = {0,0,0,0};
  #pragma unroll
  for(int i=0;i<4;i++){
    int row = m0 + ty*4 + i;
    if(row >= M) continue;
    float v[4];
    #pragma unroll
    for(int j=0;j<4;j++){
      v[j] = acc[i][j];
      if(bias) v[j] += bias[col0+j];
    }
    if(EPI==1){
      float a = ampv[row], iv = invv[row];
      const float* tr = Tm + (size_t)row*384 + col0;
      #pragma unroll
      for(int j=0;j<4;j++) v[j] += tr[j] + a*tr[128+j] + iv*tr[256+j];
    }
    *(float4*)(C + (size_t)row*ldc + col0) = make_float4(v[0],v[1],v[2],v[3]);
    if(EPI==2){
      #pragma unroll
      for(int j=0;j<4;j++){ s[j]+=v[j]; q[j]+=v[j]*v[j]; }
    }
  }
  if(EPI==2){
    __syncthreads();
    float* rs = &As[0][0];
    float* rq = &Bs[0][0];
    #pragma unroll
    for(int j=0;j<4;j++){ rs[ty*64 + tx*4 + j] = s[j]; rq[ty*64 + tx*4 + j] = q[j]; }
    __syncthreads();
    if(ty==0){
      #pragma unroll
      for(int j=0;j<4;j++){
        int col = tx*4 + j;
        float ts=0.f, tq=0.f;
        for(int t=0;t<16;t++){ ts += rs[t*64+col]; tq += rq[t*64+col]; }
        atomicAdd(&bnsum[n0+col], ts);
        atomicAdd(&bnsq[n0+col], tq);
      }
    }
  }
}

// ---------------- PNA aggregation: one block per node ----------------
__launch_bounds__(128)
__global__ void k_agg(const int* __restrict__ rp, const int* __restrict__ src_csr,
                      const float* __restrict__ ea_csr, const float* __restrict__ Kf,
                      const float* __restrict__ Amat, const float* __restrict__ Bmat,
                      float* __restrict__ agg, float* __restrict__ ampv, float* __restrict__ invv){
  const int n = blockIdx.x, c = threadIdx.x;
  const int s0 = rp[n], e0 = rp[n+1];
  const int deg = e0 - s0;
  float kcol[16];
  #pragma unroll
  for(int k=0;k<16;k++) kcol[k] = Kf[k*128+c];
  const float base = Amat[(size_t)n*128+c] + Kf[16*128+c];
  float sum=0.f, sq=0.f, mn=INFINITY, mx=-INFINITY;
  __shared__ float ea_s[16][16];
  __shared__ int src_s[16];
  for(int j0=s0; j0<e0; j0+=16){
    int cnt = min(16, e0-j0);
    __syncthreads();
    int ee = c>>4, kk = c&15;
    if(ee < cnt)   ea_s[ee][kk]   = ea_csr[(size_t)(j0+ee)*16+kk];
    if(ee+8 < cnt) ea_s[ee+8][kk] = ea_csr[(size_t)(j0+ee+8)*16+kk];
    if(c < cnt) src_s[c] = src_csr[j0+c];
    __syncthreads();
    for(int e=0;e<cnt;e++){
      float m = base + Bmat[(size_t)src_s[e]*128 + c];
      #pragma unroll
      for(int k=0;k<16;k++) m += ea_s[e][k]*kcol[k];
      sum += m; sq += m*m; mn = fminf(mn,m); mx = fmaxf(mx,m);
    }
  }
  float degc = (float)(deg>0?deg:1);
  float mean = sum/degc;
  float var  = sq/degc - mean*mean;
  var = fmaxf(var, 0.f);
  float sd = sqrtf(var + EPS_STD);
  if(deg==0){ mn=0.f; mx=0.f; }
  size_t o = (size_t)n*512;
  agg[o+c]=mean; agg[o+128+c]=mn; agg[o+256+c]=mx; agg[o+384+c]=sd;
  if(c==0){
    float amp = logf(degc+1.f)/AVG_LOG;
    ampv[n]=amp; invv[n]=1.f/amp;
  }
}

// ---------------- batchnorm ----------------
__global__ void k_bn_fin(const float* __restrict__ bnsum, const float* __restrict__ bnsq,
                         const float* __restrict__ gamma, const float* __restrict__ beta,
                         float* __restrict__ scale, float* __restrict__ shift){
  int c = threadIdx.x;
  float mu  = bnsum[c]*(1.f/NN);
  float var = bnsq[c]*(1.f/NN) - mu*mu;
  var = fmaxf(var, 0.f);
  float inv = 1.f/sqrtf(var + EPS_BN);
  float sc = gamma[c]*inv;
  scale[c] = sc;
  shift[c] = beta[c] - mu*sc;
}

__global__ void k_bn_relu(const float* __restrict__ y, const float* __restrict__ scale,
                          const float* __restrict__ shift, float* __restrict__ h){
  int i = blockIdx.x*256 + threadIdx.x;
  if(i >= NN*32) return;   // NN*128/4 vec4 groups
  int c0 = (i & 31)*4;
  float4 v = ((const float4*)y)[i];
  v.x = fmaxf(v.x*scale[c0+0]+shift[c0+0], 0.f);
  v.y = fmaxf(v.y*scale[c0+1]+shift[c0+1], 0.f);
  v.z = fmaxf(v.z*scale[c0+2]+shift[c0+2], 0.f);
  v.w = fmaxf(v.w*scale[c0+3]+shift[c0+3], 0.f);
  ((float4*)h)[i] = v;
}

// ---------------- pooling + head ----------------
__launch_bounds__(128)
__global__ void k_pool(const float* __restrict__ h, const int* __restrict__ batch,
                       float* __restrict__ g){
  int c = threadIdx.x;
  int r0 = blockIdx.x*512;
  int r1 = min(r0+512, NN);
  int cur = batch[r0] & 31;
  float acc = 0.f;
  for(int r=r0;r<r1;r++){
    int b = batch[r] & 31;
    if(b != cur){ atomicAdd(&g[(size_t)cur*128+c], acc); acc=0.f; cur=b; }
    acc += h[(size_t)r*128+c];
  }
  atomicAdd(&g[(size_t)cur*128+c], acc);
}

__launch_bounds__(256)
__global__ void k_head(const float* __restrict__ g, const float* __restrict__ W1,
                       const float* __restrict__ b1, const float* __restrict__ W2,
                       const float* __restrict__ b2, void* __restrict__ out,
                       const int* __restrict__ flag){
  __shared__ float gs[32][128];
  __shared__ float zs[32][64];
  int tid = threadIdx.x;
  for(int i=tid;i<32*128;i+=256) gs[i>>7][i&127] = g[i];
  __syncthreads();
  for(int i=tid;i<32*64;i+=256){
    int r=i>>6, c=i&63;
    float a = b1[c];
    for(int k=0;k<128;k++) a += gs[r][k]*W1[k*64+c];
    zs[r][c] = fmaxf(a, 0.f);
  }
  __syncthreads();
  const int isbf = *flag;
  for(int i=tid;i<NGR*NOUT;i+=256){
    int r = i/NOUT, c = i%NOUT;
    float a = b2[c];
    for(int k=0;k<64;k++) a += zs[r][k]*W2[k*12+c];
    if(isbf){
      union { float f; unsigned int ui; } u; u.f = a;
      // round-to-nearest-even bf16
      unsigned int lsb = (u.ui >> 16) & 1u;
      u.ui += 0x7FFFu + lsb;
      ((ushort_t*)out)[i] = (ushort_t)(u.ui >> 16);
    } else {
      ((float*)out)[i] = a;
    }
  }
}

// ---------------- host ----------------
extern "C" void kernel_launch(void* const* d_in, const int* in_sizes, int n_in,
                              void* d_out, int out_size, void* d_ws, size_t ws_size,
                              hipStream_t stream){
  // Input ORDER dispatch: dict (x, edge_attr, edge_index, batch) vs signature
  // (x, edge_index, batch, edge_attr) via in_sizes[1] (7.68M vs 960000).
  const void* x_raw = d_in[0];
  const void* ea_raw;
  const int*  eidx;
  const int*  batch;
  if(in_sizes[1] == 2*NE){           // signature order
    eidx   = (const int*)d_in[1];
    batch  = (const int*)d_in[2];
    ea_raw = d_in[3];
  } else {                           // dict order
    ea_raw = d_in[1];
    eidx   = (const int*)d_in[2];
    batch  = (const int*)d_in[3];
  }
  const void* nembW_r = d_in[4];
  const void* nembB_r = d_in[5];
  const void* eembW_r = d_in[6];
  const void* eembB_r = d_in[7];
  const void* encW_r  = d_in[8];
  const void* encB_r  = d_in[9];
  const void* preW_r  = d_in[10];
  const void* preB_r  = d_in[11];
  const void* postW_r = d_in[12];
  const void* postB_r = d_in[13];
  const void* linW_r  = d_in[14];
  const void* linB_r  = d_in[15];
  const void* bnG_r   = d_in[16];
  const void* bnB_r   = d_in[17];
  const void* h1W_r   = d_in[18];
  const void* h1B_r   = d_in[19];
  const void* h2W_r   = d_in[20];
  const void* h2B_r   = d_in[21];

  char* p = (char*)d_ws;
  auto alloc = [&](size_t bytes)->void*{
    void* r = (void*)p; p += (bytes + 255) & ~(size_t)255; return r;
  };
  int*   dtflag  = (int*)  alloc(sizeof(int)*16);
  int*   deg     = (int*)  alloc(sizeof(int)*NN);
  int*   fill    = (int*)  alloc(sizeof(int)*NN);
  int*   rp      = (int*)  alloc(sizeof(int)*(NN+1));
  int*   src_csr = (int*)  alloc(sizeof(int)*NE);
  int*   eix_csr = (int*)  alloc(sizeof(int)*NE);
  float* ea_csr  = (float*)alloc(sizeof(float)*(size_t)NE*16);
  float* h       = (float*)alloc(sizeof(float)*(size_t)NN*128);
  float* Amat    = (float*)alloc(sizeof(float)*(size_t)NN*128);
  float* Bmat    = (float*)alloc(sizeof(float)*(size_t)NN*128);
  float* agg     = (float*)alloc(sizeof(float)*(size_t)NN*512);
  float* Tm      = (float*)alloc(sizeof(float)*(size_t)NN*384);
  float* ampv    = (float*)alloc(sizeof(float)*NN);
  float* invv    = (float*)alloc(sizeof(float)*NN);
  float* Kf      = (float*)alloc(sizeof(float)*4*17*128);
  float* Wcat    = (float*)alloc(sizeof(float)*(size_t)4*512*384);
  float* bnstat  = (float*)alloc(sizeof(float)*256);
  float* bnscale = (float*)alloc(sizeof(float)*128);
  float* bnshift = (float*)alloc(sizeof(float)*128);
  float* g       = (float*)alloc(sizeof(float)*32*128);
  // fp32 weight copies
  float* nembW   = (float*)alloc(sizeof(float)*64*128);
  float* nembB   = (float*)alloc(sizeof(float)*128);
  float* eembW   = (float*)alloc(sizeof(float)*16*128);
  float* eembB   = (float*)alloc(sizeof(float)*128);
  float* encW    = (float*)alloc(sizeof(float)*4*128*128);
  float* encB    = (float*)alloc(sizeof(float)*4*128);
  float* preW    = (float*)alloc(sizeof(float)*4*384*128);
  float* preB    = (float*)alloc(sizeof(float)*4*128);
  float* postW   = (float*)alloc(sizeof(float)*(size_t)4*1664*128);
  float* postB   = (float*)alloc(sizeof(float)*4*128);
  float* linW    = (float*)alloc(sizeof(float)*4*128*128);
  float* linB    = (float*)alloc(sizeof(float)*4*128);
  float* bnG     = (float*)alloc(sizeof(float)*4*128);
  float* bnB     = (float*)alloc(sizeof(float)*4*128);
  float* h1W     = (float*)alloc(sizeof(float)*128*64);
  float* h1B     = (float*)alloc(sizeof(float)*64);
  float* h2W     = (float*)alloc(sizeof(float)*64*12);
  float* h2B     = (float*)alloc(sizeof(float)*12);
  float* x32     = (float*)alloc(sizeof(float)*(size_t)NN*64);

  CvtArgs ca;
  ca.flag = dtflag;
  int ji = 0;
  auto job = [&](const void* s, float* d, int n){ ca.j[ji].s=s; ca.j[ji].d=d; ca.j[ji].n=n; ji++; };
  job(x_raw,   x32,   NN*64);
  job(nembW_r, nembW, 64*128);
  job(nembB_r, nembB, 128);
  job(eembW_r, eembW, 16*128);
  job(eembB_r, eembB, 128);
  job(encW_r,  encW,  4*128*128);
  job(encB_r,  encB,  4*128);
  job(preW_r,  preW,  4*384*128);
  job(preB_r,  preB,  4*128);
  job(postW_r, postW, 4*1664*128);
  job(postB_r, postB, 4*128);
  job(linW_r,  linW,  4*128*128);
  job(linB_r,  linB,  4*128);
  job(bnG_r,   bnG,   4*128);
  job(bnB_r,   bnB,   4*128);
  job(h1W_r,   h1W,   128*64);
  job(h1B_r,   h1B,   64);
  job(h2W_r,   h2W,   64*12);
  job(h2B_r,   h2B,   12);

  const int* esrc = eidx;
  const int* edst = eidx + NE;

  hipMemsetAsync(deg, 0, sizeof(int)*NN, stream);
  hipMemsetAsync(fill, 0, sizeof(int)*NN, stream);
  hipMemsetAsync(g, 0, sizeof(float)*32*128, stream);

  k_detect<<<1, 256, 0, stream>>>((const ushort_t*)x_raw, dtflag);
  k_cvt<<<dim3(512, NJOBS), 256, 0, stream>>>(ca);

  k_deg<<<(NE+255)/256, 256, 0, stream>>>(edst, deg);
  k_scan<<<1, 1024, 0, stream>>>(deg, rp);
  k_scatter<<<(NE+255)/256, 256, 0, stream>>>(esrc, edst, rp, fill, src_csr, eix_csr);
  k_gather_ea<<<(NE+127)/128, 128, 0, stream>>>(eix_csr, ea_raw, ea_csr, dtflag);
  k_prep_K<<<4, 128, 0, stream>>>(eembW, eembB, encW, encB, preW, preB, Kf);
  k_prep_Wcat<<<3072, 256, 0, stream>>>(postW, Wcat);

  dim3 g2((NN+63)/64, 2), g6((NN+63)/64, 6);

  // h = x @ node_emb_W + b   (K=64)
  k_gemm<0><<<g2, 256, 0, stream>>>(x32, nembW, h, NN, 64, 128, 128,
                                    nembB, nullptr, nullptr, nullptr, nullptr, nullptr);

  for(int l=0; l<NLAYER; l++){
    const float* pW = preW + (size_t)l*384*128;
    // A = h@P1 (dst part), B = h@P2 (src part)
    k_gemm<0><<<g2, 256, 0, stream>>>(h, pW, Amat, NN, 128, 128, 128,
                                      nullptr, nullptr, nullptr, nullptr, nullptr, nullptr);
    k_gemm<0><<<g2, 256, 0, stream>>>(h, pW + 128*128, Bmat, NN, 128, 128, 128,
                                      nullptr, nullptr, nullptr, nullptr, nullptr, nullptr);
    // aggregation (edge message on the fly: A[dst] + B[src] + ea@Kf)
    k_agg<<<NN, 128, 0, stream>>>(rp, src_csr, ea_csr, Kf + (size_t)l*17*128,
                                  Amat, Bmat, agg, ampv, invv);
    // T = agg @ Wcat_l   [N,512]x[512,384]
    k_gemm<0><<<g6, 256, 0, stream>>>(agg, Wcat + (size_t)l*512*384, Tm, NN, 512, 384, 384,
                                      nullptr, nullptr, nullptr, nullptr, nullptr, nullptr);
    // z = h@W0 + T0 + amp*T1 + inv*T2 + post_b   (z reuses Bmat: dead after k_agg)
    float* z = Bmat;
    k_gemm<1><<<g2, 256, 0, stream>>>(h, postW + (size_t)l*1664*128, z, NN, 128, 128, 128,
                                      postB + l*128, Tm, ampv, invv, nullptr, nullptr);
    // y = z@linW + lin_b (+ BN stats)           (y reuses Amat: dead after k_agg)
    float* y = Amat;
    hipMemsetAsync(bnstat, 0, sizeof(float)*256, stream);
    k_gemm<2><<<g2, 256, 0, stream>>>(z, linW + (size_t)l*128*128, y, NN, 128, 128, 128,
                                      linB + l*128, nullptr, nullptr, nullptr, bnstat, bnstat+128);
    k_bn_fin<<<1, 128, 0, stream>>>(bnstat, bnstat+128, bnG + l*128, bnB + l*128,
                                    bnscale, bnshift);
    k_bn_relu<<<3750, 256, 0, stream>>>(y, bnscale, bnshift, h);
  }

  k_pool<<<(NN+511)/512, 128, 0, stream>>>(h, batch, g);
  k_head<<<1, 256, 0, stream>>>(g, h1W, h1B, h2W, h2B, d_out, dtflag);
}

// Round 6
// 1194.287 us; speedup vs baseline: 1.7634x; 1.7634x over previous
//
#include <hip/hip_runtime.h>
#include <hip/hip_bf16.h>
#include <math.h>

#define NN 30000
#define NE 480000
#define NLAYER 4
#define NGR 32
#define NOUT 12
#define EPS_BN 1e-5f
#define EPS_STD 1e-5f
#define AVG_LOG 1.3821454785305053f

typedef unsigned short ushort_t;
typedef __bf16 bf16x8 __attribute__((ext_vector_type(8)));
typedef float floatx4 __attribute__((ext_vector_type(4)));

__device__ __forceinline__ float bfu(ushort_t u){
  union { unsigned int ui; float f; } c; c.ui = ((unsigned int)u) << 16; return c.f;
}
__device__ __forceinline__ ushort_t f2bf(float f){
  union { float f; unsigned int u; } c; c.f = f;
  unsigned int lsb = (c.u >> 16) & 1u;
  c.u += 0x7FFFu + lsb;
  return (ushort_t)(c.u >> 16);
}

// ---------------- runtime dtype detection ----------------
__device__ __forceinline__ int plausible(unsigned int bits32){
  unsigned int e = (bits32 >> 23) & 0xFF;
  if(e == 0xFF) return 0;
  if(bits32 == 0 || bits32 == 0x80000000u) return 1;
  return (e >= 93 && e <= 140) ? 1 : 0;
}

__global__ void k_detect(const ushort_t* __restrict__ xr, int* __restrict__ flag){
  __shared__ int cnt[2];
  if(threadIdx.x < 2) cnt[threadIdx.x] = 0;
  __syncthreads();
  const unsigned int* xf = (const unsigned int*)xr;
  int gf = 0, gb = 0;
  for(int i = threadIdx.x; i < 1024; i += 256){
    gf += plausible(xf[i]);
    gb += plausible(((unsigned int)xr[i]) << 16);
  }
  atomicAdd(&cnt[0], gf);
  atomicAdd(&cnt[1], gb);
  __syncthreads();
  if(threadIdx.x == 0) *flag = (cnt[1] >= cnt[0]) ? 1 : 0;
}

// ---------------- batched conversion to fp32 ----------------
#define NJOBS 19
struct CvtJob { const void* s; float* d; int n; };
struct CvtArgs { CvtJob j[NJOBS]; const int* flag; };

__global__ void k_cvt(CvtArgs a){
  int ji = blockIdx.y;
  const int isbf = *a.flag;
  float* d = a.j[ji].d;
  int n = a.j[ji].n;
  if(isbf){
    const ushort_t* s = (const ushort_t*)a.j[ji].s;
    for(int i = blockIdx.x*256 + threadIdx.x; i < n; i += gridDim.x*256) d[i] = bfu(s[i]);
  } else {
    const float* s = (const float*)a.j[ji].s;
    for(int i = blockIdx.x*256 + threadIdx.x; i < n; i += gridDim.x*256) d[i] = s[i];
  }
}

// x -> bf16
__global__ void k_xbf(const void* __restrict__ x, ushort_t* __restrict__ d,
                      const int* __restrict__ flag){
  int i = blockIdx.x*256 + threadIdx.x;
  if(i >= NN*64) return;
  if(*flag) d[i] = ((const ushort_t*)x)[i];
  else      d[i] = f2bf(((const float*)x)[i]);
}

// ---------------- weight transposes to bf16 [N,K] ----------------
#define NTR 29
struct TrJob { const float* s; ushort_t* d; int K, N; };
struct TrArgs { TrJob j[NTR]; };

__global__ void k_tr(TrArgs a){
  TrJob j = a.j[blockIdx.y];
  int total = j.K * j.N;
  for(int i = blockIdx.x*256 + threadIdx.x; i < total; i += gridDim.x*256){
    int n = i / j.K, k = i % j.K;
    j.d[i] = f2bf(j.s[(size_t)k * j.N + n]);
  }
}

// ---------------- CSR build ----------------
__global__ void k_deg(const int* __restrict__ dst, int* __restrict__ deg){
  int i = blockIdx.x*256 + threadIdx.x;
  if(i < NE){
    unsigned d = (unsigned)dst[i];
    if(d < NN) atomicAdd(&deg[d], 1);
  }
}

__global__ void k_scan(const int* __restrict__ deg, int* __restrict__ rp){
  __shared__ int wsum[16];
  __shared__ int carry;
  int tid = threadIdx.x, lane = tid & 63, wid = tid >> 6;
  if(tid==0){ carry = 0; rp[0] = 0; }
  __syncthreads();
  for(int base=0; base<NN; base+=1024){
    int i = base + tid;
    int v = (i<NN) ? deg[i] : 0;
    int incl = v;
    #pragma unroll
    for(int off=1; off<64; off<<=1){
      int t = __shfl_up(incl, off, 64);
      if(lane >= off) incl += t;
    }
    if(lane==63) wsum[wid] = incl;
    __syncthreads();
    int woff = 0;
    for(int wI=0; wI<wid; wI++) woff += wsum[wI];
    if(i<NN) rp[i+1] = carry + woff + incl;
    __syncthreads();
    if(tid==0){
      int t = 0;
      for(int wI=0; wI<16; wI++) t += wsum[wI];
      carry += t;
    }
    __syncthreads();
  }
}

__global__ void k_scatter(const int* __restrict__ src, const int* __restrict__ dst,
                          const int* __restrict__ rp, int* __restrict__ fill,
                          int* __restrict__ src_csr, int* __restrict__ eix_csr){
  int i = blockIdx.x*256 + threadIdx.x;
  if(i >= NE) return;
  unsigned d = (unsigned)dst[i];
  unsigned s = (unsigned)src[i];
  if(d >= NN || s >= NN) return;
  int pos = rp[d] + atomicAdd(&fill[d], 1);
  src_csr[pos] = (int)s;
  eix_csr[pos] = i;
}

__global__ void k_gather_ea(const int* __restrict__ eix, const void* __restrict__ ea,
                            float* __restrict__ out, const int* __restrict__ flag){
  int j = blockIdx.x*128 + threadIdx.x;
  if(j >= NE) return;
  int i = eix[j];
  float* d = out + (size_t)j*16;
  if(*flag){
    const ushort_t* s = (const ushort_t*)ea + (size_t)i*16;
    #pragma unroll
    for(int k=0;k<16;k++) d[k] = bfu(s[k]);
  } else {
    const float* s = (const float*)ea + (size_t)i*16;
    #pragma unroll
    for(int k=0;k<16;k++) d[k] = s[k];
  }
}

// ---------------- Kf prep (fp32) ----------------
__global__ void k_prep_K(const float* __restrict__ embW, const float* __restrict__ embB,
                         const float* __restrict__ encW, const float* __restrict__ encB,
                         const float* __restrict__ preW, const float* __restrict__ preB,
                         float* __restrict__ Kf){
  int l = blockIdx.x, c = threadIdx.x;
  const float* eW = encW + (size_t)l*128*128;
  const float* P3 = preW + (size_t)l*384*128 + 256*128;
  __shared__ float tmp[17][128];
  for(int r=0;r<16;r++){
    float a = 0.f;
    for(int k=0;k<128;k++) a += embW[r*128+k]*eW[k*128+c];
    tmp[r][c] = a;
  }
  {
    float a = encB[l*128+c];
    for(int k=0;k<128;k++) a += embB[k]*eW[k*128+c];
    tmp[16][c] = a;
  }
  __syncthreads();
  float* o = Kf + (size_t)l*17*128;
  for(int r=0;r<16;r++){
    float a = 0.f;
    for(int k=0;k<128;k++) a += tmp[r][k]*P3[k*128+c];
    o[r*128+c] = a;
  }
  {
    float a = preB[l*128+c];
    for(int k=0;k<128;k++) a += tmp[16][k]*P3[k*128+c];
    o[16*128+c] = a;
  }
}

// ---------------- bf16 MFMA GEMM: C[M,N] = A[M,K] @ BT[N,K]^T ----------------
// 128x128 tile, BK=64, 4 waves 2x2, each wave 4x4 tiles of 16x16x32.
// EPI 0: +bias(optional). EPI 1: +bias + T-combine (Tm stride 384, amp/inv per row).
// EPI 2: +bias + BN column stats (LDS-reduced atomics).
// OUTBF: 1 -> bf16 store, 0 -> fp32 store.
template<int EPI, int OUTBF>
__launch_bounds__(256)
__global__ void k_mm(const ushort_t* __restrict__ A, const ushort_t* __restrict__ BT,
                     void* __restrict__ C, int M, int K, int ldc,
                     const float* __restrict__ bias,
                     const float* __restrict__ Tm,
                     const float* __restrict__ ampv, const float* __restrict__ invv,
                     float* __restrict__ bnsum, float* __restrict__ bnsq){
  __shared__ __align__(16) ushort_t Als[128][88];
  __shared__ __align__(16) ushort_t Bls[128][88];
  __shared__ float s_sum[128];
  __shared__ float s_sq[128];
  const int tid = threadIdx.x;
  const int m0 = blockIdx.x*128, n0 = blockIdx.y*128;
  const int w = tid >> 6, lane = tid & 63;
  const int wm = (w & 1)*64, wn = (w >> 1)*64;
  const int quad = lane >> 4, l15 = lane & 15;
  floatx4 acc[4][4] = {};

  for(int k0=0; k0<K; k0+=64){
    #pragma unroll
    for(int i=0;i<4;i++){
      int c = tid + 256*i;
      int row = c >> 3, kc = (c & 7)*8;
      uint4 va = make_uint4(0u,0u,0u,0u);
      int gr = m0 + row;
      if(gr < M) va = *(const uint4*)(A + (size_t)gr*K + k0 + kc);
      *(uint4*)(&Als[row][kc]) = va;
      uint4 vb = *(const uint4*)(BT + (size_t)(n0+row)*K + k0 + kc);
      *(uint4*)(&Bls[row][kc]) = vb;
    }
    __syncthreads();
    #pragma unroll
    for(int ks=0; ks<64; ks+=32){
      bf16x8 a[4], b[4];
      #pragma unroll
      for(int i=0;i<4;i++) a[i] = *(const bf16x8*)(&Als[wm+16*i+l15][ks+quad*8]);
      #pragma unroll
      for(int j=0;j<4;j++) b[j] = *(const bf16x8*)(&Bls[wn+16*j+l15][ks+quad*8]);
      #pragma unroll
      for(int i=0;i<4;i++)
        #pragma unroll
        for(int j=0;j<4;j++)
          acc[i][j] = __builtin_amdgcn_mfma_f32_16x16x32_bf16(a[i], b[j], acc[i][j], 0, 0, 0);
    }
    __syncthreads();
  }

  float s[4] = {0,0,0,0}, q[4] = {0,0,0,0};
  if(EPI==2){
    if(tid < 128){ s_sum[tid] = 0.f; s_sq[tid] = 0.f; }
    __syncthreads();
  }
  #pragma unroll
  for(int i=0;i<4;i++){
    #pragma unroll
    for(int r=0;r<4;r++){
      int grow = m0 + wm + 16*i + quad*4 + r;
      if(grow >= M) continue;
      float amp = 0.f, iv = 0.f;
      const float* tr = nullptr;
      if(EPI==1){ amp = ampv[grow]; iv = invv[grow]; tr = Tm + (size_t)grow*384; }
      #pragma unroll
      for(int j=0;j<4;j++){
        int gcol = n0 + wn + 16*j + l15;
        float v = acc[i][j][r];
        if(bias) v += bias[gcol];
        if(EPI==1) v += tr[gcol] + amp*tr[128+gcol] + iv*tr[256+gcol];
        if(OUTBF) ((ushort_t*)C)[(size_t)grow*ldc + gcol] = f2bf(v);
        else      ((float*)  C)[(size_t)grow*ldc + gcol] = v;
        if(EPI==2){ s[j] += v; q[j] += v*v; }
      }
    }
  }
  if(EPI==2){
    #pragma unroll
    for(int j=0;j<4;j++){
      atomicAdd(&s_sum[wn + 16*j + l15], s[j]);
      atomicAdd(&s_sq [wn + 16*j + l15], q[j]);
    }
    __syncthreads();
    if(tid < 128){
      atomicAdd(&bnsum[n0 + tid], s_sum[tid]);
      atomicAdd(&bnsq [n0 + tid], s_sq[tid]);
    }
  }
}

// ---------------- PNA aggregation ----------------
__launch_bounds__(128)
__global__ void k_agg(const int* __restrict__ rp, const int* __restrict__ src_csr,
                      const float* __restrict__ ea_csr, const float* __restrict__ Kf,
                      const float* __restrict__ AB,
                      ushort_t* __restrict__ agg, float* __restrict__ ampv,
                      float* __restrict__ invv){
  const int n = blockIdx.x, c = threadIdx.x;
  const int s0 = rp[n], e0 = rp[n+1];
  const int deg = e0 - s0;
  float kcol[16];
  #pragma unroll
  for(int k=0;k<16;k++) kcol[k] = Kf[k*128+c];
  const float base = AB[(size_t)n*256 + c] + Kf[16*128+c];
  float sum=0.f, sq=0.f, mn=INFINITY, mx=-INFINITY;
  __shared__ float ea_s[16][16];
  __shared__ int src_s[16];
  for(int j0=s0; j0<e0; j0+=16){
    int cnt = min(16, e0-j0);
    __syncthreads();
    int ee = c>>4, kk = c&15;
    if(ee < cnt)   ea_s[ee][kk]   = ea_csr[(size_t)(j0+ee)*16+kk];
    if(ee+8 < cnt) ea_s[ee+8][kk] = ea_csr[(size_t)(j0+ee+8)*16+kk];
    if(c < cnt) src_s[c] = src_csr[j0+c];
    __syncthreads();
    for(int e=0;e<cnt;e++){
      float m = base + AB[(size_t)src_s[e]*256 + 128 + c];
      #pragma unroll
      for(int k=0;k<16;k++) m += ea_s[e][k]*kcol[k];
      sum += m; sq += m*m; mn = fminf(mn,m); mx = fmaxf(mx,m);
    }
  }
  float degc = (float)(deg>0?deg:1);
  float mean = sum/degc;
  float var  = fmaxf(sq/degc - mean*mean, 0.f);
  float sd = sqrtf(var + EPS_STD);
  if(deg==0){ mn=0.f; mx=0.f; }
  ushort_t* o = agg + (size_t)n*512;
  o[c]       = f2bf(mean);
  o[128+c]   = f2bf(mn);
  o[256+c]   = f2bf(mx);
  o[384+c]   = f2bf(sd);
  if(c==0){
    float amp = logf(degc+1.f)/AVG_LOG;
    ampv[n] = amp; invv[n] = 1.f/amp;
  }
}

// ---------------- batchnorm ----------------
__global__ void k_bn_fin(const float* __restrict__ bnsum, const float* __restrict__ bnsq,
                         const float* __restrict__ gamma, const float* __restrict__ beta,
                         float* __restrict__ scale, float* __restrict__ shift){
  int c = threadIdx.x;
  float mu  = bnsum[c]*(1.f/NN);
  float var = fmaxf(bnsq[c]*(1.f/NN) - mu*mu, 0.f);
  float inv = 1.f/sqrtf(var + EPS_BN);
  float sc = gamma[c]*inv;
  scale[c] = sc;
  shift[c] = beta[c] - mu*sc;
}

__global__ void k_bn_relu(const float* __restrict__ y, const float* __restrict__ scale,
                          const float* __restrict__ shift, ushort_t* __restrict__ h){
  int i = blockIdx.x*256 + threadIdx.x;
  if(i >= NN*128) return;
  int c = i & 127;
  float v = fmaxf(y[i]*scale[c] + shift[c], 0.f);
  h[i] = f2bf(v);
}

// ---------------- pooling + head ----------------
__launch_bounds__(128)
__global__ void k_pool(const ushort_t* __restrict__ h, const int* __restrict__ batch,
                       float* __restrict__ g){
  int c = threadIdx.x;
  int r0 = blockIdx.x*512;
  int r1 = min(r0+512, NN);
  int cur = batch[r0] & 31;
  float acc = 0.f;
  for(int r=r0;r<r1;r++){
    int b = batch[r] & 31;
    if(b != cur){ atomicAdd(&g[(size_t)cur*128+c], acc); acc=0.f; cur=b; }
    acc += bfu(h[(size_t)r*128+c]);
  }
  atomicAdd(&g[(size_t)cur*128+c], acc);
}

__launch_bounds__(256)
__global__ void k_head(const float* __restrict__ g, const float* __restrict__ W1,
                       const float* __restrict__ b1, const float* __restrict__ W2,
                       const float* __restrict__ b2, void* __restrict__ out,
                       const int* __restrict__ flag){
  __shared__ float gs[32][128];
  __shared__ float zs[32][64];
  int tid = threadIdx.x;
  for(int i=tid;i<32*128;i+=256) gs[i>>7][i&127] = g[i];
  __syncthreads();
  for(int i=tid;i<32*64;i+=256){
    int r=i>>6, c=i&63;
    float a = b1[c];
    for(int k=0;k<128;k++) a += gs[r][k]*W1[k*64+c];
    zs[r][c] = fmaxf(a, 0.f);
  }
  __syncthreads();
  const int isbf = *flag;
  for(int i=tid;i<NGR*NOUT;i+=256){
    int r = i/NOUT, c = i%NOUT;
    float a = b2[c];
    for(int k=0;k<64;k++) a += zs[r][k]*W2[k*12+c];
    if(isbf) ((ushort_t*)out)[i] = f2bf(a);
    else     ((float*)out)[i] = a;
  }
}

// ---------------- host ----------------
extern "C" void kernel_launch(void* const* d_in, const int* in_sizes, int n_in,
                              void* d_out, int out_size, void* d_ws, size_t ws_size,
                              hipStream_t stream){
  const void* x_raw = d_in[0];
  const void* ea_raw;
  const int*  eidx;
  const int*  batch;
  if(in_sizes[1] == 2*NE){           // signature order
    eidx   = (const int*)d_in[1];
    batch  = (const int*)d_in[2];
    ea_raw = d_in[3];
  } else {                           // dict order
    ea_raw = d_in[1];
    eidx   = (const int*)d_in[2];
    batch  = (const int*)d_in[3];
  }
  const void* nembW_r = d_in[4];
  const void* nembB_r = d_in[5];
  const void* eembW_r = d_in[6];
  const void* eembB_r = d_in[7];
  const void* encW_r  = d_in[8];
  const void* encB_r  = d_in[9];
  const void* preW_r  = d_in[10];
  const void* preB_r  = d_in[11];
  const void* postW_r = d_in[12];
  const void* postB_r = d_in[13];
  const void* linW_r  = d_in[14];
  const void* linB_r  = d_in[15];
  const void* bnG_r   = d_in[16];
  const void* bnB_r   = d_in[17];
  const void* h1W_r   = d_in[18];
  const void* h1B_r   = d_in[19];
  const void* h2W_r   = d_in[20];
  const void* h2B_r   = d_in[21];

  char* p = (char*)d_ws;
  auto alloc = [&](size_t bytes)->void*{
    void* r = (void*)p; p += (bytes + 255) & ~(size_t)255; return r;
  };
  int*      dtflag  = (int*)     alloc(sizeof(int)*16);
  int*      deg     = (int*)     alloc(sizeof(int)*NN);
  int*      fill    = (int*)     alloc(sizeof(int)*NN);
  int*      rp      = (int*)     alloc(sizeof(int)*(NN+1));
  int*      src_csr = (int*)     alloc(sizeof(int)*NE);
  int*      eix_csr = (int*)     alloc(sizeof(int)*NE);
  float*    ea_csr  = (float*)   alloc(sizeof(float)*(size_t)NE*16);
  ushort_t* xbf     = (ushort_t*)alloc(sizeof(ushort_t)*(size_t)NN*64);
  ushort_t* h       = (ushort_t*)alloc(sizeof(ushort_t)*(size_t)NN*128);
  ushort_t* aggb    = (ushort_t*)alloc(sizeof(ushort_t)*(size_t)NN*512);
  ushort_t* z       = (ushort_t*)alloc(sizeof(ushort_t)*(size_t)NN*128);
  float*    AB      = (float*)   alloc(sizeof(float)*(size_t)NN*256);
  float*    Tm      = (float*)   alloc(sizeof(float)*(size_t)NN*384);
  float*    y       = (float*)   alloc(sizeof(float)*(size_t)NN*128);
  float*    ampv    = (float*)   alloc(sizeof(float)*NN);
  float*    invv    = (float*)   alloc(sizeof(float)*NN);
  float*    Kf      = (float*)   alloc(sizeof(float)*4*17*128);
  float*    bnstat  = (float*)   alloc(sizeof(float)*256);
  float*    bnscale = (float*)   alloc(sizeof(float)*128);
  float*    bnshift = (float*)   alloc(sizeof(float)*128);
  float*    g       = (float*)   alloc(sizeof(float)*32*128);
  // bf16 transposed weights [N,K]
  ushort_t* WembT   = (ushort_t*)alloc(sizeof(ushort_t)*128*64);
  ushort_t* P12T    = (ushort_t*)alloc(sizeof(ushort_t)*4*256*128);
  ushort_t* WcatT   = (ushort_t*)alloc(sizeof(ushort_t)*(size_t)4*384*512);
  ushort_t* W0T     = (ushort_t*)alloc(sizeof(ushort_t)*4*128*128);
  ushort_t* linWT   = (ushort_t*)alloc(sizeof(ushort_t)*4*128*128);
  // fp32 weight copies
  float* nembW = (float*)alloc(sizeof(float)*64*128);
  float* nembB = (float*)alloc(sizeof(float)*128);
  float* eembW = (float*)alloc(sizeof(float)*16*128);
  float* eembB = (float*)alloc(sizeof(float)*128);
  float* encW  = (float*)alloc(sizeof(float)*4*128*128);
  float* encB  = (float*)alloc(sizeof(float)*4*128);
  float* preW  = (float*)alloc(sizeof(float)*4*384*128);
  float* preB  = (float*)alloc(sizeof(float)*4*128);
  float* postW = (float*)alloc(sizeof(float)*(size_t)4*1664*128);
  float* postB = (float*)alloc(sizeof(float)*4*128);
  float* linW  = (float*)alloc(sizeof(float)*4*128*128);
  float* linB  = (float*)alloc(sizeof(float)*4*128);
  float* bnG   = (float*)alloc(sizeof(float)*4*128);
  float* bnB   = (float*)alloc(sizeof(float)*4*128);
  float* h1W   = (float*)alloc(sizeof(float)*128*64);
  float* h1B   = (float*)alloc(sizeof(float)*64);
  float* h2W   = (float*)alloc(sizeof(float)*64*12);
  float* h2B   = (float*)alloc(sizeof(float)*12);

  CvtArgs ca;
  ca.flag = dtflag;
  int ji = 0;
  auto job = [&](const void* s, float* d, int n){ ca.j[ji].s=s; ca.j[ji].d=d; ca.j[ji].n=n; ji++; };
  job(nembW_r, nembW, 64*128);
  job(nembB_r, nembB, 128);
  job(eembW_r, eembW, 16*128);
  job(eembB_r, eembB, 128);
  job(encW_r,  encW,  4*128*128);
  job(encB_r,  encB,  4*128);
  job(preW_r,  preW,  4*384*128);
  job(preB_r,  preB,  4*128);
  job(postW_r, postW, 4*1664*128);
  job(postB_r, postB, 4*128);
  job(linW_r,  linW,  4*128*128);
  job(linB_r,  linB,  4*128);
  job(bnG_r,   bnG,   4*128);
  job(bnB_r,   bnB,   4*128);
  job(h1W_r,   h1W,   128*64);
  job(h1B_r,   h1B,   64);
  job(h2W_r,   h2W,   64*12);
  job(h2B_r,   h2B,   12);
  job(h2B_r,   h2B,   12);  // pad to NJOBS (harmless duplicate)

  // transpose jobs: dst[n*K+k] = src[k*N+n]
  TrArgs ta;
  int ti = 0;
  auto tj = [&](const float* s, ushort_t* d, int K, int N){ ta.j[ti].s=s; ta.j[ti].d=d; ta.j[ti].K=K; ta.j[ti].N=N; ti++; };
  tj(nembW, WembT, 64, 128);
  for(int l=0;l<4;l++){
    const float* pw = preW + (size_t)l*384*128;
    tj(pw,            P12T + (size_t)l*256*128,           128, 128);  // P1 -> rows 0..127
    tj(pw + 128*128,  P12T + (size_t)l*256*128 + 128*128, 128, 128);  // P2 -> rows 128..255
    const float* po = postW + (size_t)l*1664*128;
    for(int b=0;b<3;b++)
      tj(po + (size_t)(128 + b*512)*128, WcatT + (size_t)l*384*512 + (size_t)b*128*512, 512, 128);
    tj(po, W0T + (size_t)l*128*128, 128, 128);                        // W0
    tj(linW + (size_t)l*128*128, linWT + (size_t)l*128*128, 128, 128);
  }

  const int* esrc = eidx;
  const int* edst = eidx + NE;

  hipMemsetAsync(deg, 0, sizeof(int)*NN, stream);
  hipMemsetAsync(fill, 0, sizeof(int)*NN, stream);
  hipMemsetAsync(g, 0, sizeof(float)*32*128, stream);

  k_detect<<<1, 256, 0, stream>>>((const ushort_t*)x_raw, dtflag);
  k_cvt<<<dim3(256, NJOBS), 256, 0, stream>>>(ca);
  k_xbf<<<(NN*64+255)/256, 256, 0, stream>>>(x_raw, xbf, dtflag);
  k_tr<<<dim3(32, NTR), 256, 0, stream>>>(ta);

  k_deg<<<(NE+255)/256, 256, 0, stream>>>(edst, deg);
  k_scan<<<1, 1024, 0, stream>>>(deg, rp);
  k_scatter<<<(NE+255)/256, 256, 0, stream>>>(esrc, edst, rp, fill, src_csr, eix_csr);
  k_gather_ea<<<(NE+127)/128, 128, 0, stream>>>(eix_csr, ea_raw, ea_csr, dtflag);
  k_prep_K<<<4, 128, 0, stream>>>(eembW, eembB, encW, encB, preW, preB, Kf);

  const int MB = (NN + 127)/128;  // 235

  // h = x @ Wemb + b  (bf16 out)
  k_mm<0,1><<<dim3(MB,1), 256, 0, stream>>>(xbf, WembT, h, NN, 64, 128,
                                            nembB, nullptr, nullptr, nullptr, nullptr, nullptr);

  for(int l=0; l<NLAYER; l++){
    // AB = h @ [P1|P2]  (fp32 out, N=256)
    k_mm<0,0><<<dim3(MB,2), 256, 0, stream>>>(h, P12T + (size_t)l*256*128, AB, NN, 128, 256,
                                              nullptr, nullptr, nullptr, nullptr, nullptr, nullptr);
    k_agg<<<NN, 128, 0, stream>>>(rp, src_csr, ea_csr, Kf + (size_t)l*17*128,
                                  AB, aggb, ampv, invv);
    // Tm = agg @ WcatT^T  (fp32 out, K=512, N=384)
    k_mm<0,0><<<dim3(MB,3), 256, 0, stream>>>(aggb, WcatT + (size_t)l*384*512, Tm, NN, 512, 384,
                                              nullptr, nullptr, nullptr, nullptr, nullptr, nullptr);
    // z = h @ W0 + postB + T0 + amp*T1 + inv*T2  (bf16 out)
    k_mm<1,1><<<dim3(MB,1), 256, 0, stream>>>(h, W0T + (size_t)l*128*128, z, NN, 128, 128,
                                              postB + l*128, Tm, ampv, invv, nullptr, nullptr);
    // y = z @ linW + linB  (fp32 out + BN stats)
    hipMemsetAsync(bnstat, 0, sizeof(float)*256, stream);
    k_mm<2,0><<<dim3(MB,1), 256, 0, stream>>>(z, linWT + (size_t)l*128*128, y, NN, 128, 128,
                                              linB + l*128, nullptr, nullptr, nullptr,
                                              bnstat, bnstat+128);
    k_bn_fin<<<1, 128, 0, stream>>>(bnstat, bnstat+128, bnG + l*128, bnB + l*128,
                                    bnscale, bnshift);
    k_bn_relu<<<(NN*128+255)/256, 256, 0, stream>>>(y, bnscale, bnshift, h);
  }

  k_pool<<<(NN+511)/512, 128, 0, stream>>>(h, batch, g);
  k_head<<<1, 256, 0, stream>>>(g, h1W, h1B, h2W, h2B, d_out, dtflag);
}

// Round 8
// 1165.173 us; speedup vs baseline: 1.8074x; 1.0250x over previous
//
#include <hip/hip_runtime.h>
#include <hip/hip_bf16.h>
#include <math.h>

#define NN 30000
#define NE 480000
#define NLAYER 4
#define NGR 32
#define NOUT 12
#define EPS_BN 1e-5f
#define EPS_STD 1e-5f
#define AVG_LOG 1.3821454785305053f
#define MB_GRID 235   // (NN+127)/128

typedef unsigned short ushort_t;
typedef __bf16 bf16x8 __attribute__((ext_vector_type(8)));
typedef float floatx4 __attribute__((ext_vector_type(4)));

__device__ __forceinline__ float bfu(ushort_t u){
  union { unsigned int ui; float f; } c; c.ui = ((unsigned int)u) << 16; return c.f;
}
__device__ __forceinline__ ushort_t f2bf(float f){
  union { float f; unsigned int u; } c; c.f = f;
  unsigned int lsb = (c.u >> 16) & 1u;
  c.u += 0x7FFFu + lsb;
  return (ushort_t)(c.u >> 16);
}

// ---------------- runtime dtype detection ----------------
__device__ __forceinline__ int plausible(unsigned int bits32){
  unsigned int e = (bits32 >> 23) & 0xFF;
  if(e == 0xFF) return 0;
  if(bits32 == 0 || bits32 == 0x80000000u) return 1;
  return (e >= 93 && e <= 140) ? 1 : 0;
}

__global__ void k_detect(const ushort_t* __restrict__ xr, int* __restrict__ flag){
  __shared__ int cnt[2];
  if(threadIdx.x < 2) cnt[threadIdx.x] = 0;
  __syncthreads();
  const unsigned int* xf = (const unsigned int*)xr;
  int gf = 0, gb = 0;
  for(int i = threadIdx.x; i < 1024; i += 256){
    gf += plausible(xf[i]);
    gb += plausible(((unsigned int)xr[i]) << 16);
  }
  atomicAdd(&cnt[0], gf);
  atomicAdd(&cnt[1], gb);
  __syncthreads();
  if(threadIdx.x == 0) *flag = (cnt[1] >= cnt[0]) ? 1 : 0;
}

// ---------------- batched conversion to fp32 ----------------
#define NJOBS 18
struct CvtJob { const void* s; float* d; int n; };
struct CvtArgs { CvtJob j[NJOBS]; const int* flag; };

__global__ void k_cvt(CvtArgs a){
  int ji = blockIdx.y;
  const int isbf = *a.flag;
  float* d = a.j[ji].d;
  int n = a.j[ji].n;
  if(isbf){
    const ushort_t* s = (const ushort_t*)a.j[ji].s;
    for(int i = blockIdx.x*256 + threadIdx.x; i < n; i += gridDim.x*256) d[i] = bfu(s[i]);
  } else {
    const float* s = (const float*)a.j[ji].s;
    for(int i = blockIdx.x*256 + threadIdx.x; i < n; i += gridDim.x*256) d[i] = s[i];
  }
}

__global__ void k_xbf(const void* __restrict__ x, ushort_t* __restrict__ d,
                      const int* __restrict__ flag){
  int i = blockIdx.x*256 + threadIdx.x;
  if(i >= NN*64) return;
  if(*flag) d[i] = ((const ushort_t*)x)[i];
  else      d[i] = f2bf(((const float*)x)[i]);
}

// ---------------- tiled transpose fp32[K,N] -> bf16[N,K] ----------------
#define NTR 9
struct TrJob { const float* s; ushort_t* d; int K, N; };
struct TrArgs { TrJob j[NTR]; };

__global__ void k_tr(TrArgs a){
  TrJob j = a.j[blockIdx.y];
  int nk = j.K >> 6, nn = j.N >> 6;
  int tile = blockIdx.x;
  if(tile >= nk*nn) return;
  int tk = tile % nk, tn = tile / nk;
  int k0 = tk*64, n0 = tn*64;
  __shared__ float t[64][65];
  int w = threadIdx.x >> 6, c = threadIdx.x & 63;
  #pragma unroll
  for(int i=0;i<16;i+=1){
    int r = i*4 + w;
    t[r][c] = j.s[(size_t)(k0+r)*j.N + n0 + c];
  }
  __syncthreads();
  #pragma unroll
  for(int i=0;i<16;i+=1){
    int r = i*4 + w;
    j.d[(size_t)(n0+r)*j.K + k0 + c] = f2bf(t[c][r]);
  }
}

// ---------------- fold: D[n,k] = sum_t S1[k,t]*S2[t,n]  (bf16 out) ----------------
#define NFOLD 16
struct FoldJob { const float* s1; const float* s2; ushort_t* d; int Kd; };
struct FoldArgs { FoldJob j[NFOLD]; };

__global__ void k_fold(FoldArgs a){
  FoldJob j = a.j[blockIdx.y];
  const int n0 = blockIdx.x*16;
  __shared__ float s2s[128][16];
  int tid = threadIdx.x;
  for(int idx = tid; idx < 128*16; idx += 256){
    int t = idx >> 4, jj = idx & 15;
    s2s[t][jj] = j.s2[t*128 + n0 + jj];
  }
  __syncthreads();
  for(int k = tid; k < j.Kd; k += 256){
    float part[16];
    #pragma unroll
    for(int p=0;p<16;p++) part[p] = 0.f;
    for(int t0=0; t0<128; t0+=32){
      float rr[32];
      #pragma unroll
      for(int tt=0;tt<32;tt++) rr[tt] = j.s1[(size_t)k*128 + t0 + tt];
      #pragma unroll
      for(int p=0;p<16;p++){
        float acc = 0.f;
        #pragma unroll
        for(int tt=0;tt<32;tt++) acc += rr[tt]*s2s[t0+tt][p];
        part[p] += acc;
      }
    }
    #pragma unroll
    for(int p=0;p<16;p++)
      j.d[(size_t)(n0+p)*j.Kd + k] = f2bf(part[p]);
  }
}

__global__ void k_foldb(const float* __restrict__ postB, const float* __restrict__ linW,
                        const float* __restrict__ linB, float* __restrict__ biasY){
  int l = blockIdx.x, c = threadIdx.x;
  float a = linB[l*128+c];
  const float* L = linW + (size_t)l*128*128;
  const float* pb = postB + l*128;
  for(int t=0;t<128;t++) a += pb[t]*L[t*128+c];
  biasY[l*128+c] = a;
}

// ---------------- CSR build ----------------
__global__ void k_deg(const int* __restrict__ dst, int* __restrict__ deg){
  int i = blockIdx.x*256 + threadIdx.x;
  if(i < NE){
    unsigned d = (unsigned)dst[i];
    if(d < NN) atomicAdd(&deg[d], 1);
  }
}

__global__ void k_scan1(const int* __restrict__ deg, int* __restrict__ rp,
                        int* __restrict__ bsum){
  __shared__ int wsum[16];
  int tid = threadIdx.x, lane = tid & 63, wid = tid >> 6;
  int i = blockIdx.x*1024 + tid;
  int v = (i < NN) ? deg[i] : 0;
  int incl = v;
  #pragma unroll
  for(int off=1; off<64; off<<=1){
    int t = __shfl_up(incl, off, 64);
    if(lane >= off) incl += t;
  }
  if(lane==63) wsum[wid] = incl;
  __syncthreads();
  int woff = 0;
  for(int w=0; w<wid; w++) woff += wsum[w];
  if(i < NN) rp[i+1] = incl + woff;
  if(tid == 0){
    int t = 0;
    for(int w=0; w<16; w++) t += wsum[w];
    bsum[blockIdx.x] = t;
  }
}

__global__ void k_scan2(const int* __restrict__ bsum, int* __restrict__ boff,
                        int* __restrict__ rp, int nb){
  if(threadIdx.x == 0){
    int run = 0;
    for(int b=0;b<nb;b++){ boff[b] = run; run += bsum[b]; }
    rp[0] = 0;
  }
}

__global__ void k_scan3(int* __restrict__ rp, const int* __restrict__ boff){
  int i = blockIdx.x*1024 + threadIdx.x;
  if(i < NN) rp[i+1] += boff[blockIdx.x];
}

__global__ void k_scatter(const int* __restrict__ src, const int* __restrict__ dst,
                          const int* __restrict__ rp, int* __restrict__ fill,
                          int* __restrict__ src_csr, int* __restrict__ eix_csr){
  int i = blockIdx.x*256 + threadIdx.x;
  if(i >= NE) return;
  unsigned d = (unsigned)dst[i];
  unsigned s = (unsigned)src[i];
  if(d >= NN || s >= NN) return;
  int pos = rp[d] + atomicAdd(&fill[d], 1);
  src_csr[pos] = (int)s;
  eix_csr[pos] = i;
}

// canonical per-node order (sort segment by edge index) -> launch-to-launch determinism
__global__ void k_srt(const int* __restrict__ rp, int* __restrict__ eix,
                      int* __restrict__ src){
  int n = blockIdx.x*256 + threadIdx.x;
  if(n >= NN) return;
  int s0 = rp[n], e0 = rp[n+1];
  for(int i=s0+1;i<e0;i++){
    int ke = eix[i], ks = src[i];
    int j = i-1;
    while(j >= s0 && eix[j] > ke){
      eix[j+1] = eix[j]; src[j+1] = src[j]; j--;
    }
    eix[j+1] = ke; src[j+1] = ks;
  }
}

__global__ void k_gather_ea(const int* __restrict__ eix, const void* __restrict__ ea,
                            ushort_t* __restrict__ out, const int* __restrict__ flag){
  int j = blockIdx.x*128 + threadIdx.x;
  if(j >= NE) return;
  int i = eix[j];
  uint4* d = (uint4*)(out + (size_t)j*16);
  if(*flag){
    const uint4* s = (const uint4*)((const ushort_t*)ea + (size_t)i*16);
    d[0] = s[0]; d[1] = s[1];
  } else {
    const float* s = (const float*)ea + (size_t)i*16;
    union { ushort_t us[16]; uint4 u4[2]; } pk;
    #pragma unroll
    for(int k=0;k<16;k++) pk.us[k] = f2bf(s[k]);
    d[0] = pk.u4[0]; d[1] = pk.u4[1];
  }
}

// ---------------- Kf prep ----------------
__global__ void k_prep_K(const float* __restrict__ embW, const float* __restrict__ embB,
                         const float* __restrict__ encW, const float* __restrict__ encB,
                         const float* __restrict__ preW, const float* __restrict__ preB,
                         float* __restrict__ Kf){
  int bx = blockIdx.x;
  int l = bx / 17, r = bx % 17;
  int c = threadIdx.x;
  const float* eW = encW + (size_t)l*128*128;
  const float* P3 = preW + (size_t)l*384*128 + 256*128;
  __shared__ float trow[128];
  float a;
  if(r < 16){
    a = 0.f;
    const float* w = embW + r*128;
    for(int k=0;k<128;k++) a += w[k]*eW[k*128+c];
  } else {
    a = encB[l*128+c];
    for(int k=0;k<128;k++) a += embB[k]*eW[k*128+c];
  }
  trow[c] = a;
  __syncthreads();
  float o = (r==16) ? preB[l*128+c] : 0.f;
  for(int k=0;k<128;k++) o += trow[k]*P3[k*128+c];
  Kf[(size_t)l*17*128 + r*128 + c] = o;
}

// ---------------- bf16 MFMA GEMM: C[M,N] = A[M,K] @ BT[N,K]^T ----------------
// EPI 0: +bias(optional). EPI 1: +bias + T-combine + per-block BN partials (no atomics).
template<int EPI, int OUTBF>
__launch_bounds__(256)
__global__ void k_mm(const ushort_t* __restrict__ A, const ushort_t* __restrict__ BT,
                     void* __restrict__ C, int M, int K, int ldc,
                     const float* __restrict__ bias,
                     const float* __restrict__ Tm,
                     const float* __restrict__ ampv, const float* __restrict__ invv,
                     float* __restrict__ bnpart){
  __shared__ __align__(16) ushort_t Als[128][88];
  __shared__ __align__(16) ushort_t Bls[128][88];
  __shared__ float s_part[8][128];
  __shared__ float q_part[8][128];
  const int tid = threadIdx.x;
  const int m0 = blockIdx.x*128, n0 = blockIdx.y*128;
  const int w = tid >> 6, lane = tid & 63;
  const int wm = (w & 1)*64, wn = (w >> 1)*64;
  const int quad = lane >> 4, l15 = lane & 15;
  floatx4 acc[4][4] = {};

  for(int k0=0; k0<K; k0+=64){
    #pragma unroll
    for(int i=0;i<4;i++){
      int c = tid + 256*i;
      int row = c >> 3, kc = (c & 7)*8;
      uint4 va = make_uint4(0u,0u,0u,0u);
      int gr = m0 + row;
      if(gr < M) va = *(const uint4*)(A + (size_t)gr*K + k0 + kc);
      *(uint4*)(&Als[row][kc]) = va;
      uint4 vb = *(const uint4*)(BT + (size_t)(n0+row)*K + k0 + kc);
      *(uint4*)(&Bls[row][kc]) = vb;
    }
    __syncthreads();
    #pragma unroll
    for(int ks=0; ks<64; ks+=32){
      bf16x8 a[4], b[4];
      #pragma unroll
      for(int i=0;i<4;i++) a[i] = *(const bf16x8*)(&Als[wm+16*i+l15][ks+quad*8]);
      #pragma unroll
      for(int j=0;j<4;j++) b[j] = *(const bf16x8*)(&Bls[wn+16*j+l15][ks+quad*8]);
      #pragma unroll
      for(int i=0;i<4;i++)
        #pragma unroll
        for(int j=0;j<4;j++)
          acc[i][j] = __builtin_amdgcn_mfma_f32_16x16x32_bf16(a[i], b[j], acc[i][j], 0, 0, 0);
    }
    __syncthreads();
  }

  float s[4] = {0,0,0,0}, q[4] = {0,0,0,0};
  #pragma unroll
  for(int i=0;i<4;i++){
    #pragma unroll
    for(int r=0;r<4;r++){
      int grow = m0 + wm + 16*i + quad*4 + r;
      if(grow >= M) continue;
      float amp = 0.f, iv = 0.f;
      const float* tr = nullptr;
      if(EPI==1){ amp = ampv[grow]; iv = invv[grow]; tr = Tm + (size_t)grow*384; }
      #pragma unroll
      for(int j=0;j<4;j++){
        int gcol = n0 + wn + 16*j + l15;
        float v = acc[i][j][r];
        if(bias) v += bias[gcol];
        if(EPI==1) v += tr[gcol] + amp*tr[128+gcol] + iv*tr[256+gcol];
        if(OUTBF) ((ushort_t*)C)[(size_t)grow*ldc + gcol] = f2bf(v);
        else      ((float*)  C)[(size_t)grow*ldc + gcol] = v;
        if(EPI==1){ s[j] += v; q[j] += v*v; }
      }
    }
  }
  if(EPI==1){
    // deterministic: unique (slot,col) per thread, fixed-order reduce
    const int slot = (w & 1)*4 + quad;
    #pragma unroll
    for(int j=0;j<4;j++){
      s_part[slot][wn + 16*j + l15] = s[j];
      q_part[slot][wn + 16*j + l15] = q[j];
    }
    __syncthreads();
    if(tid < 128){
      float ss = 0.f, qq = 0.f;
      #pragma unroll
      for(int sl=0; sl<8; sl++){ ss += s_part[sl][tid]; qq += q_part[sl][tid]; }
      bnpart[(size_t)blockIdx.x*256 + tid]       = ss;
      bnpart[(size_t)blockIdx.x*256 + 128 + tid] = qq;
    }
  }
}

// ---------------- PNA aggregation (AB fp32, ea bf16) ----------------
__launch_bounds__(128)
__global__ void k_agg(const int* __restrict__ rp, const int* __restrict__ src_csr,
                      const ushort_t* __restrict__ ea_csr, const float* __restrict__ Kf,
                      const float* __restrict__ AB,
                      ushort_t* __restrict__ agg, float* __restrict__ ampv,
                      float* __restrict__ invv){
  const int n = blockIdx.x, c = threadIdx.x;
  const int s0 = rp[n], e0 = rp[n+1];
  const int deg = e0 - s0;
  float kcol[16];
  #pragma unroll
  for(int k=0;k<16;k++) kcol[k] = Kf[k*128+c];
  const float base = AB[(size_t)n*256 + c] + Kf[16*128+c];
  float sum=0.f, sq=0.f, mn=INFINITY, mx=-INFINITY;
  __shared__ float ea_s[16][16];
  __shared__ int src_s[16];
  for(int j0=s0; j0<e0; j0+=16){
    int cnt = min(16, e0-j0);
    __syncthreads();
    int ee = c>>4, kk = c&15;
    if(ee < cnt)   ea_s[ee][kk]   = bfu(ea_csr[(size_t)(j0+ee)*16+kk]);
    if(ee+8 < cnt) ea_s[ee+8][kk] = bfu(ea_csr[(size_t)(j0+ee+8)*16+kk]);
    if(c < cnt) src_s[c] = src_csr[j0+c];
    __syncthreads();
    for(int e=0;e<cnt;e++){
      float m = base + AB[(size_t)src_s[e]*256 + 128 + c];
      #pragma unroll
      for(int k=0;k<16;k++) m += ea_s[e][k]*kcol[k];
      sum += m; sq += m*m; mn = fminf(mn,m); mx = fmaxf(mx,m);
    }
  }
  float degc = (float)(deg>0?deg:1);
  float mean = sum/degc;
  float var  = fmaxf(sq/degc - mean*mean, 0.f);
  float sd = sqrtf(var + EPS_STD);
  if(deg==0){ mn=0.f; mx=0.f; }
  ushort_t* o = agg + (size_t)n*512;
  o[c]     = f2bf(mean);
  o[128+c] = f2bf(mn);
  o[256+c] = f2bf(mx);
  o[384+c] = f2bf(sd);
  if(c==0){
    float amp = logf(degc+1.f)/AVG_LOG;
    ampv[n] = amp; invv[n] = 1.f/amp;
  }
}

// ---------------- batchnorm (deterministic reduce of per-block partials) ----------------
__global__ void k_bn_fin(const float* __restrict__ bnpart, int nb,
                         const float* __restrict__ gamma, const float* __restrict__ beta,
                         float* __restrict__ scale, float* __restrict__ shift){
  int c = threadIdx.x;
  float s = 0.f, q = 0.f;
  for(int b=0;b<nb;b++){
    s += bnpart[(size_t)b*256 + c];
    q += bnpart[(size_t)b*256 + 128 + c];
  }
  float mu  = s*(1.f/NN);
  float var = fmaxf(q*(1.f/NN) - mu*mu, 0.f);
  float inv = 1.f/sqrtf(var + EPS_BN);
  float sc = gamma[c]*inv;
  scale[c] = sc;
  shift[c] = beta[c] - mu*sc;
}

__global__ void k_bn_relu(const float* __restrict__ y, const float* __restrict__ scale,
                          const float* __restrict__ shift, ushort_t* __restrict__ h){
  int i = blockIdx.x*256 + threadIdx.x;
  if(i >= NN*128) return;
  int c = i & 127;
  float v = fmaxf(y[i]*scale[c] + shift[c], 0.f);
  h[i] = f2bf(v);
}

// ---------------- pooling (deterministic, chunked) + head ----------------
__device__ __forceinline__ int lbound(const int* a, int n, int v){
  int lo = 0, hi = n;
  while(lo < hi){ int mid = (lo+hi) >> 1; if(a[mid] < v) lo = mid+1; else hi = mid; }
  return lo;
}

__launch_bounds__(128)
__global__ void k_pool1(const ushort_t* __restrict__ h, const int* __restrict__ batch,
                        float* __restrict__ gpart){
  int b = blockIdx.x, ch = blockIdx.y, c = threadIdx.x;
  int lo = lbound(batch, NN, b), hi = lbound(batch, NN, b+1);
  int len = hi - lo;
  int per = (len + 7) >> 3;
  int r0 = min(lo + ch*per, hi);
  int r1 = min(r0 + per, hi);
  float acc = 0.f;
  for(int r=r0;r<r1;r++) acc += bfu(h[(size_t)r*128+c]);
  gpart[((size_t)b*8 + ch)*128 + c] = acc;
}

__global__ void k_pool2(const float* __restrict__ gpart, float* __restrict__ g){
  int b = blockIdx.x, c = threadIdx.x;
  float acc = 0.f;
  #pragma unroll
  for(int ch=0; ch<8; ch++) acc += gpart[((size_t)b*8 + ch)*128 + c];
  g[(size_t)b*128 + c] = acc;
}

__launch_bounds__(64)
__global__ void k_head(const float* __restrict__ g, const float* __restrict__ W1,
                       const float* __restrict__ b1, const float* __restrict__ W2,
                       const float* __restrict__ b2, void* __restrict__ out,
                       const int* __restrict__ flag){
  __shared__ float gs[128];
  __shared__ float zs[64];
  int r = blockIdx.x, tid = threadIdx.x;
  gs[tid] = g[r*128 + tid];
  gs[tid+64] = g[r*128 + tid + 64];
  __syncthreads();
  float a = b1[tid];
  for(int k=0;k<128;k++) a += gs[k]*W1[k*64+tid];
  zs[tid] = fmaxf(a, 0.f);
  __syncthreads();
  if(tid < NOUT){
    float o = b2[tid];
    for(int k=0;k<64;k++) o += zs[k]*W2[k*12+tid];
    if(*flag) ((ushort_t*)out)[r*NOUT + tid] = f2bf(o);
    else      ((float*)out)[r*NOUT + tid] = o;
  }
}

// ---------------- host ----------------
extern "C" void kernel_launch(void* const* d_in, const int* in_sizes, int n_in,
                              void* d_out, int out_size, void* d_ws, size_t ws_size,
                              hipStream_t stream){
  const void* x_raw = d_in[0];
  const void* ea_raw;
  const int*  eidx;
  const int*  batch;
  if(in_sizes[1] == 2*NE){           // signature order
    eidx   = (const int*)d_in[1];
    batch  = (const int*)d_in[2];
    ea_raw = d_in[3];
  } else {                           // dict order
    ea_raw = d_in[1];
    eidx   = (const int*)d_in[2];
    batch  = (const int*)d_in[3];
  }
  const void* nembW_r = d_in[4];
  const void* nembB_r = d_in[5];
  const void* eembW_r = d_in[6];
  const void* eembB_r = d_in[7];
  const void* encW_r  = d_in[8];
  const void* encB_r  = d_in[9];
  const void* preW_r  = d_in[10];
  const void* preB_r  = d_in[11];
  const void* postW_r = d_in[12];
  const void* postB_r = d_in[13];
  const void* linW_r  = d_in[14];
  const void* linB_r  = d_in[15];
  const void* bnG_r   = d_in[16];
  const void* bnB_r   = d_in[17];
  const void* h1W_r   = d_in[18];
  const void* h1B_r   = d_in[19];
  const void* h2W_r   = d_in[20];
  const void* h2B_r   = d_in[21];

  char* p = (char*)d_ws;
  auto alloc = [&](size_t bytes)->void*{
    void* r = (void*)p; p += (bytes + 255) & ~(size_t)255; return r;
  };
  int*      dtflag  = (int*)     alloc(sizeof(int)*16);
  int*      deg     = (int*)     alloc(sizeof(int)*NN);
  int*      fill    = (int*)     alloc(sizeof(int)*NN);
  int*      rp      = (int*)     alloc(sizeof(int)*(NN+1));
  int*      bsum    = (int*)     alloc(sizeof(int)*64);
  int*      boff    = (int*)     alloc(sizeof(int)*64);
  int*      src_csr = (int*)     alloc(sizeof(int)*NE);
  int*      eix_csr = (int*)     alloc(sizeof(int)*NE);
  ushort_t* ea_csr  = (ushort_t*)alloc(sizeof(ushort_t)*(size_t)NE*16);
  ushort_t* xbf     = (ushort_t*)alloc(sizeof(ushort_t)*(size_t)NN*64);
  ushort_t* h       = (ushort_t*)alloc(sizeof(ushort_t)*(size_t)NN*128);
  ushort_t* aggb    = (ushort_t*)alloc(sizeof(ushort_t)*(size_t)NN*512);
  float*    AB      = (float*)   alloc(sizeof(float)*(size_t)NN*256);
  float*    Tm      = (float*)   alloc(sizeof(float)*(size_t)NN*384);
  float*    y       = (float*)   alloc(sizeof(float)*(size_t)NN*128);
  float*    ampv    = (float*)   alloc(sizeof(float)*NN);
  float*    invv    = (float*)   alloc(sizeof(float)*NN);
  float*    Kf      = (float*)   alloc(sizeof(float)*4*17*128);
  float*    bnpart  = (float*)   alloc(sizeof(float)*(size_t)MB_GRID*256);
  float*    bnscale = (float*)   alloc(sizeof(float)*128);
  float*    bnshift = (float*)   alloc(sizeof(float)*128);
  float*    gpart   = (float*)   alloc(sizeof(float)*32*8*128);
  float*    g       = (float*)   alloc(sizeof(float)*32*128);
  float*    biasY   = (float*)   alloc(sizeof(float)*4*128);
  ushort_t* WembT   = (ushort_t*)alloc(sizeof(ushort_t)*128*64);
  ushort_t* P12T    = (ushort_t*)alloc(sizeof(ushort_t)*4*256*128);
  ushort_t* WcatFT  = (ushort_t*)alloc(sizeof(ushort_t)*(size_t)4*384*512);
  ushort_t* W0FT    = (ushort_t*)alloc(sizeof(ushort_t)*4*128*128);
  float* nembW = (float*)alloc(sizeof(float)*64*128);
  float* nembB = (float*)alloc(sizeof(float)*128);
  float* eembW = (float*)alloc(sizeof(float)*16*128);
  float* eembB = (float*)alloc(sizeof(float)*128);
  float* encW  = (float*)alloc(sizeof(float)*4*128*128);
  float* encB  = (float*)alloc(sizeof(float)*4*128);
  float* preW  = (float*)alloc(sizeof(float)*4*384*128);
  float* preB  = (float*)alloc(sizeof(float)*4*128);
  float* postW = (float*)alloc(sizeof(float)*(size_t)4*1664*128);
  float* postB = (float*)alloc(sizeof(float)*4*128);
  float* linW  = (float*)alloc(sizeof(float)*4*128*128);
  float* linB  = (float*)alloc(sizeof(float)*4*128);
  float* bnG   = (float*)alloc(sizeof(float)*4*128);
  float* bnB   = (float*)alloc(sizeof(float)*4*128);
  float* h1W   = (float*)alloc(sizeof(float)*128*64);
  float* h1B   = (float*)alloc(sizeof(float)*64);
  float* h2W   = (float*)alloc(sizeof(float)*64*12);
  float* h2B   = (float*)alloc(sizeof(float)*12);

  CvtArgs ca;
  ca.flag = dtflag;
  int ji = 0;
  auto job = [&](const void* s, float* d, int n){ ca.j[ji].s=s; ca.j[ji].d=d; ca.j[ji].n=n; ji++; };
  job(nembW_r, nembW, 64*128);
  job(nembB_r, nembB, 128);
  job(eembW_r, eembW, 16*128);
  job(eembB_r, eembB, 128);
  job(encW_r,  encW,  4*128*128);
  job(encB_r,  encB,  4*128);
  job(preW_r,  preW,  4*384*128);
  job(preB_r,  preB,  4*128);
  job(postW_r, postW, 4*1664*128);
  job(postB_r, postB, 4*128);
  job(linW_r,  linW,  4*128*128);
  job(linB_r,  linB,  4*128);
  job(bnG_r,   bnG,   4*128);
  job(bnB_r,   bnB,   4*128);
  job(h1W_r,   h1W,   128*64);
  job(h1B_r,   h1B,   64);
  job(h2W_r,   h2W,   64*12);
  job(h2B_r,   h2B,   12);

  TrArgs ta;
  int ti = 0;
  auto tj = [&](const float* s, ushort_t* d, int K, int N){ ta.j[ti].s=s; ta.j[ti].d=d; ta.j[ti].K=K; ta.j[ti].N=N; ti++; };
  tj(nembW, WembT, 64, 128);
  for(int l=0;l<4;l++){
    const float* pw = preW + (size_t)l*384*128;
    tj(pw,           P12T + (size_t)l*256*128,           128, 128);
    tj(pw + 128*128, P12T + (size_t)l*256*128 + 128*128, 128, 128);
  }

  FoldArgs fa;
  int fi = 0;
  for(int l=0;l<4;l++){
    const float* po = postW + (size_t)l*1664*128;
    const float* L  = linW + (size_t)l*128*128;
    for(int b=0;b<3;b++){
      fa.j[fi].s1 = po + (size_t)(128 + b*512)*128;
      fa.j[fi].s2 = L;
      fa.j[fi].d  = WcatFT + (size_t)l*384*512 + (size_t)b*128*512;
      fa.j[fi].Kd = 512;
      fi++;
    }
    fa.j[fi].s1 = po;
    fa.j[fi].s2 = L;
    fa.j[fi].d  = W0FT + (size_t)l*128*128;
    fa.j[fi].Kd = 128;
    fi++;
  }

  const int* esrc = eidx;
  const int* edst = eidx + NE;

  hipMemsetAsync(deg, 0, sizeof(int)*NN, stream);
  hipMemsetAsync(fill, 0, sizeof(int)*NN, stream);

  k_detect<<<1, 256, 0, stream>>>((const ushort_t*)x_raw, dtflag);
  k_cvt<<<dim3(128, NJOBS), 256, 0, stream>>>(ca);
  k_xbf<<<(NN*64+255)/256, 256, 0, stream>>>(x_raw, xbf, dtflag);
  k_tr<<<dim3(4, NTR), 256, 0, stream>>>(ta);
  k_fold<<<dim3(8, NFOLD), 256, 0, stream>>>(fa);
  k_foldb<<<4, 128, 0, stream>>>(postB, linW, linB, biasY);
  k_prep_K<<<68, 128, 0, stream>>>(eembW, eembB, encW, encB, preW, preB, Kf);

  k_deg<<<(NE+255)/256, 256, 0, stream>>>(edst, deg);
  k_scan1<<<30, 1024, 0, stream>>>(deg, rp, bsum);
  k_scan2<<<1, 64, 0, stream>>>(bsum, boff, rp, 30);
  k_scan3<<<30, 1024, 0, stream>>>(rp, boff);
  k_scatter<<<(NE+255)/256, 256, 0, stream>>>(esrc, edst, rp, fill, src_csr, eix_csr);
  k_srt<<<(NN+255)/256, 256, 0, stream>>>(rp, eix_csr, src_csr);
  k_gather_ea<<<(NE+127)/128, 128, 0, stream>>>(eix_csr, ea_raw, ea_csr, dtflag);

  // h = x @ Wemb + b  (bf16 out)
  k_mm<0,1><<<dim3(MB_GRID,1), 256, 0, stream>>>(xbf, WembT, h, NN, 64, 128,
                                                 nembB, nullptr, nullptr, nullptr, nullptr);

  for(int l=0; l<NLAYER; l++){
    // AB = h @ [P1|P2]  (fp32 out, N=256)
    k_mm<0,0><<<dim3(MB_GRID,2), 256, 0, stream>>>(h, P12T + (size_t)l*256*128, AB, NN, 128, 256,
                                                   nullptr, nullptr, nullptr, nullptr, nullptr);
    k_agg<<<NN, 128, 0, stream>>>(rp, src_csr, ea_csr, Kf + (size_t)l*17*128,
                                  AB, aggb, ampv, invv);
    // Tm = aggb @ (Wcat@linW)^T  (fp32 out, K=512, N=384)
    k_mm<0,0><<<dim3(MB_GRID,3), 256, 0, stream>>>(aggb, WcatFT + (size_t)l*384*512, Tm, NN, 512, 384,
                                                   nullptr, nullptr, nullptr, nullptr, nullptr);
    // y = h @ (W0@linW) + biasY + T-combine  (+ deterministic BN partials)
    k_mm<1,0><<<dim3(MB_GRID,1), 256, 0, stream>>>(h, W0FT + (size_t)l*128*128, y, NN, 128, 128,
                                                   biasY + l*128, Tm, ampv, invv, bnpart);
    k_bn_fin<<<1, 128, 0, stream>>>(bnpart, MB_GRID, bnG + l*128, bnB + l*128,
                                    bnscale, bnshift);
    k_bn_relu<<<(NN*128+255)/256, 256, 0, stream>>>(y, bnscale, bnshift, h);
  }

  k_pool1<<<dim3(NGR,8), 128, 0, stream>>>(h, batch, gpart);
  k_pool2<<<NGR, 128, 0, stream>>>(gpart, g);
  k_head<<<NGR, 64, 0, stream>>>(g, h1W, h1B, h2W, h2B, d_out, dtflag);
}

// Round 9
// 1031.047 us; speedup vs baseline: 2.0426x; 1.1301x over previous
//
#include <hip/hip_runtime.h>
#include <hip/hip_bf16.h>
#include <math.h>

#define NN 30000
#define NE 480000
#define NLAYER 4
#define NGR 32
#define NOUT 12
#define EPS_BN 1e-5f
#define EPS_STD 1e-5f
#define AVG_LOG 1.3821454785305053f
#define MB_GRID 235   // (NN+127)/128

typedef unsigned short ushort_t;
typedef __bf16 bf16x8 __attribute__((ext_vector_type(8)));
typedef float floatx4 __attribute__((ext_vector_type(4)));

__device__ __forceinline__ float bfu(ushort_t u){
  union { unsigned int ui; float f; } c; c.ui = ((unsigned int)u) << 16; return c.f;
}
__device__ __forceinline__ ushort_t f2bf(float f){
  union { float f; unsigned int u; } c; c.f = f;
  unsigned int lsb = (c.u >> 16) & 1u;
  c.u += 0x7FFFu + lsb;
  return (ushort_t)(c.u >> 16);
}

// ---------------- runtime dtype detection ----------------
__device__ __forceinline__ int plausible(unsigned int bits32){
  unsigned int e = (bits32 >> 23) & 0xFF;
  if(e == 0xFF) return 0;
  if(bits32 == 0 || bits32 == 0x80000000u) return 1;
  return (e >= 93 && e <= 140) ? 1 : 0;
}

__global__ void k_detect(const ushort_t* __restrict__ xr, int* __restrict__ flag){
  __shared__ int cnt[2];
  if(threadIdx.x < 2) cnt[threadIdx.x] = 0;
  __syncthreads();
  const unsigned int* xf = (const unsigned int*)xr;
  int gf = 0, gb = 0;
  for(int i = threadIdx.x; i < 1024; i += 256){
    gf += plausible(xf[i]);
    gb += plausible(((unsigned int)xr[i]) << 16);
  }
  atomicAdd(&cnt[0], gf);
  atomicAdd(&cnt[1], gb);
  __syncthreads();
  if(threadIdx.x == 0) *flag = (cnt[1] >= cnt[0]) ? 1 : 0;
}

// ---------------- batched conversion to fp32 ----------------
#define NJOBS 18
struct CvtJob { const void* s; float* d; int n; };
struct CvtArgs { CvtJob j[NJOBS]; const int* flag; };

__global__ void k_cvt(CvtArgs a){
  int ji = blockIdx.y;
  const int isbf = *a.flag;
  float* d = a.j[ji].d;
  int n = a.j[ji].n;
  if(isbf){
    const ushort_t* s = (const ushort_t*)a.j[ji].s;
    for(int i = blockIdx.x*256 + threadIdx.x; i < n; i += gridDim.x*256) d[i] = bfu(s[i]);
  } else {
    const float* s = (const float*)a.j[ji].s;
    for(int i = blockIdx.x*256 + threadIdx.x; i < n; i += gridDim.x*256) d[i] = s[i];
  }
}

__global__ void k_xbf(const void* __restrict__ x, ushort_t* __restrict__ d,
                      const int* __restrict__ flag){
  int i = blockIdx.x*256 + threadIdx.x;
  if(i >= NN*64) return;
  if(*flag) d[i] = ((const ushort_t*)x)[i];
  else      d[i] = f2bf(((const float*)x)[i]);
}

// ---------------- tiled transpose fp32[K,N] -> bf16[N,K] ----------------
#define NTR 9
struct TrJob { const float* s; ushort_t* d; int K, N; };
struct TrArgs { TrJob j[NTR]; };

__global__ void k_tr(TrArgs a){
  TrJob j = a.j[blockIdx.y];
  int nk = j.K >> 6, nn = j.N >> 6;
  int tile = blockIdx.x;
  if(tile >= nk*nn) return;
  int tk = tile % nk, tn = tile / nk;
  int k0 = tk*64, n0 = tn*64;
  __shared__ float t[64][65];
  int w = threadIdx.x >> 6, c = threadIdx.x & 63;
  #pragma unroll
  for(int i=0;i<16;i+=1){
    int r = i*4 + w;
    t[r][c] = j.s[(size_t)(k0+r)*j.N + n0 + c];
  }
  __syncthreads();
  #pragma unroll
  for(int i=0;i<16;i+=1){
    int r = i*4 + w;
    j.d[(size_t)(n0+r)*j.K + k0 + c] = f2bf(t[c][r]);
  }
}

// ---------------- fold: D[n,k] = sum_t S1[k,t]*S2[t,n]  (bf16 out) ----------------
#define NFOLD 16
struct FoldJob { const float* s1; const float* s2; ushort_t* d; int Kd; };
struct FoldArgs { FoldJob j[NFOLD]; };

__global__ void k_fold(FoldArgs a){
  FoldJob j = a.j[blockIdx.y];
  const int n0 = blockIdx.x*16;
  __shared__ float s2s[128][16];
  int tid = threadIdx.x;
  for(int idx = tid; idx < 128*16; idx += 256){
    int t = idx >> 4, jj = idx & 15;
    s2s[t][jj] = j.s2[t*128 + n0 + jj];
  }
  __syncthreads();
  for(int k = tid; k < j.Kd; k += 256){
    float part[16];
    #pragma unroll
    for(int p=0;p<16;p++) part[p] = 0.f;
    for(int t0=0; t0<128; t0+=32){
      float rr[32];
      #pragma unroll
      for(int tt=0;tt<32;tt++) rr[tt] = j.s1[(size_t)k*128 + t0 + tt];
      #pragma unroll
      for(int p=0;p<16;p++){
        float acc = 0.f;
        #pragma unroll
        for(int tt=0;tt<32;tt++) acc += rr[tt]*s2s[t0+tt][p];
        part[p] += acc;
      }
    }
    #pragma unroll
    for(int p=0;p<16;p++)
      j.d[(size_t)(n0+p)*j.Kd + k] = f2bf(part[p]);
  }
}

__global__ void k_foldb(const float* __restrict__ postB, const float* __restrict__ linW,
                        const float* __restrict__ linB, float* __restrict__ biasY){
  int l = blockIdx.x, c = threadIdx.x;
  float a = linB[l*128+c];
  const float* L = linW + (size_t)l*128*128;
  const float* pb = postB + l*128;
  for(int t=0;t<128;t++) a += pb[t]*L[t*128+c];
  biasY[l*128+c] = a;
}

// ---------------- CSR build ----------------
__global__ void k_deg(const int* __restrict__ dst, int* __restrict__ deg){
  int i = blockIdx.x*256 + threadIdx.x;
  if(i < NE){
    unsigned d = (unsigned)dst[i];
    if(d < NN) atomicAdd(&deg[d], 1);
  }
}

__global__ void k_scan1(const int* __restrict__ deg, int* __restrict__ rp,
                        int* __restrict__ bsum){
  __shared__ int wsum[16];
  int tid = threadIdx.x, lane = tid & 63, wid = tid >> 6;
  int i = blockIdx.x*1024 + tid;
  int v = (i < NN) ? deg[i] : 0;
  int incl = v;
  #pragma unroll
  for(int off=1; off<64; off<<=1){
    int t = __shfl_up(incl, off, 64);
    if(lane >= off) incl += t;
  }
  if(lane==63) wsum[wid] = incl;
  __syncthreads();
  int woff = 0;
  for(int w=0; w<wid; w++) woff += wsum[w];
  if(i < NN) rp[i+1] = incl + woff;
  if(tid == 0){
    int t = 0;
    for(int w=0; w<16; w++) t += wsum[w];
    bsum[blockIdx.x] = t;
  }
}

__global__ void k_scan2(const int* __restrict__ bsum, int* __restrict__ boff,
                        int* __restrict__ rp, int nb){
  if(threadIdx.x == 0){
    int run = 0;
    for(int b=0;b<nb;b++){ boff[b] = run; run += bsum[b]; }
    rp[0] = 0;
  }
}

__global__ void k_scan3(int* __restrict__ rp, const int* __restrict__ boff){
  int i = blockIdx.x*1024 + threadIdx.x;
  if(i < NN) rp[i+1] += boff[blockIdx.x];
}

__global__ void k_scatter(const int* __restrict__ dst,
                          const int* __restrict__ rp, int* __restrict__ fill,
                          int* __restrict__ eix_csr){
  int i = blockIdx.x*256 + threadIdx.x;
  if(i >= NE) return;
  unsigned d = (unsigned)dst[i];
  if(d >= NN) return;
  int pos = rp[d] + atomicAdd(&fill[d], 1);
  eix_csr[pos] = i;
}

// canonical per-node order: LDS insertion sort of edge ids (keys only)
__launch_bounds__(64)
__global__ void k_srt(const int* __restrict__ rp, int* __restrict__ eix){
  __shared__ int buf[64][129];   // stride 129 -> (t+i)%32 banks, 2-way max (free)
  int t = threadIdx.x;
  int n = blockIdx.x*64 + t;
  if(n >= NN) return;
  int s0 = rp[n], e0 = rp[n+1], d = e0 - s0;
  if(d <= 1) return;
  if(d <= 128){
    int* b = buf[t];
    for(int i=0;i<d;i++) b[i] = eix[s0+i];
    for(int i=1;i<d;i++){
      int k = b[i], j = i-1;
      while(j >= 0 && b[j] > k){ b[j+1] = b[j]; j--; }
      b[j+1] = k;
    }
    for(int i=0;i<d;i++) eix[s0+i] = b[i];
  } else {
    for(int i=s0+1;i<e0;i++){
      int k = eix[i], j = i-1;
      while(j >= s0 && eix[j] > k){ eix[j+1] = eix[j]; j--; }
      eix[j+1] = k;
    }
  }
}

// gather edge_attr (bf16) + src ids into CSR order
__global__ void k_gather_ea(const int* __restrict__ eix, const int* __restrict__ esrc,
                            const void* __restrict__ ea,
                            ushort_t* __restrict__ out, int* __restrict__ src_csr,
                            const int* __restrict__ flag){
  int j = blockIdx.x*128 + threadIdx.x;
  if(j >= NE) return;
  int i = eix[j];
  src_csr[j] = esrc[i];
  uint4* d = (uint4*)(out + (size_t)j*16);
  if(*flag){
    const uint4* s = (const uint4*)((const ushort_t*)ea + (size_t)i*16);
    d[0] = s[0]; d[1] = s[1];
  } else {
    const float* s = (const float*)ea + (size_t)i*16;
    union { ushort_t us[16]; uint4 u4[2]; } pk;
    #pragma unroll
    for(int k=0;k<16;k++) pk.us[k] = f2bf(s[k]);
    d[0] = pk.u4[0]; d[1] = pk.u4[1];
  }
}

// ---------------- Kf prep ----------------
__global__ void k_prep_K(const float* __restrict__ embW, const float* __restrict__ embB,
                         const float* __restrict__ encW, const float* __restrict__ encB,
                         const float* __restrict__ preW, const float* __restrict__ preB,
                         float* __restrict__ Kf){
  int bx = blockIdx.x;
  int l = bx / 17, r = bx % 17;
  int c = threadIdx.x;
  const float* eW = encW + (size_t)l*128*128;
  const float* P3 = preW + (size_t)l*384*128 + 256*128;
  __shared__ float trow[128];
  float a;
  if(r < 16){
    a = 0.f;
    const float* w = embW + r*128;
    for(int k=0;k<128;k++) a += w[k]*eW[k*128+c];
  } else {
    a = encB[l*128+c];
    for(int k=0;k<128;k++) a += embB[k]*eW[k*128+c];
  }
  trow[c] = a;
  __syncthreads();
  float o = (r==16) ? preB[l*128+c] : 0.f;
  for(int k=0;k<128;k++) o += trow[k]*P3[k*128+c];
  Kf[(size_t)l*17*128 + r*128 + c] = o;
}

// ---------------- bf16 MFMA GEMM: C[M,N] = A[M,K] @ BT[N,K]^T ----------------
// EPI 0: +bias(optional), OUTBF store type.
// EPI 2: mixed AB output: col-block 0 -> fp32 C (Ah), col-block 1 -> bf16 C2 (Bh).
template<int EPI, int OUTBF>
__launch_bounds__(256)
__global__ void k_mm(const ushort_t* __restrict__ A, const ushort_t* __restrict__ BT,
                     void* __restrict__ C, void* __restrict__ C2,
                     int M, int K, int ldc, const float* __restrict__ bias){
  __shared__ __align__(16) ushort_t Als[128][88];
  __shared__ __align__(16) ushort_t Bls[128][88];
  const int tid = threadIdx.x;
  const int m0 = blockIdx.x*128, n0 = blockIdx.y*128;
  const int w = tid >> 6, lane = tid & 63;
  const int wm = (w & 1)*64, wn = (w >> 1)*64;
  const int quad = lane >> 4, l15 = lane & 15;
  floatx4 acc[4][4] = {};

  for(int k0=0; k0<K; k0+=64){
    #pragma unroll
    for(int i=0;i<4;i++){
      int c = tid + 256*i;
      int row = c >> 3, kc = (c & 7)*8;
      uint4 va = make_uint4(0u,0u,0u,0u);
      int gr = m0 + row;
      if(gr < M) va = *(const uint4*)(A + (size_t)gr*K + k0 + kc);
      *(uint4*)(&Als[row][kc]) = va;
      uint4 vb = *(const uint4*)(BT + (size_t)(n0+row)*K + k0 + kc);
      *(uint4*)(&Bls[row][kc]) = vb;
    }
    __syncthreads();
    #pragma unroll
    for(int ks=0; ks<64; ks+=32){
      bf16x8 a[4], b[4];
      #pragma unroll
      for(int i=0;i<4;i++) a[i] = *(const bf16x8*)(&Als[wm+16*i+l15][ks+quad*8]);
      #pragma unroll
      for(int j=0;j<4;j++) b[j] = *(const bf16x8*)(&Bls[wn+16*j+l15][ks+quad*8]);
      #pragma unroll
      for(int i=0;i<4;i++)
        #pragma unroll
        for(int j=0;j<4;j++)
          acc[i][j] = __builtin_amdgcn_mfma_f32_16x16x32_bf16(a[i], b[j], acc[i][j], 0, 0, 0);
    }
    __syncthreads();
  }

  #pragma unroll
  for(int i=0;i<4;i++){
    #pragma unroll
    for(int r=0;r<4;r++){
      int grow = m0 + wm + 16*i + quad*4 + r;
      if(grow >= M) continue;
      #pragma unroll
      for(int j=0;j<4;j++){
        int gcol = n0 + wn + 16*j + l15;
        float v = acc[i][j][r];
        if(EPI==0){
          if(bias) v += bias[gcol];
          if(OUTBF) ((ushort_t*)C)[(size_t)grow*ldc + gcol] = f2bf(v);
          else      ((float*)  C)[(size_t)grow*ldc + gcol] = v;
        } else {  // EPI==2 mixed
          if(n0 == 0) ((float*)C)[(size_t)grow*128 + gcol] = v;
          else        ((ushort_t*)C2)[(size_t)grow*128 + (gcol-128)] = f2bf(v);
        }
      }
    }
  }
}

// ---------------- fused post GEMM: y = agg@Wcat (3 amp-panels) + h@W0f + biasY ----------------
// bf16 y out + deterministic per-block BN partials.
__launch_bounds__(256)
__global__ void k_post(const ushort_t* __restrict__ aggb, const ushort_t* __restrict__ h,
                       const ushort_t* __restrict__ Wcat, const ushort_t* __restrict__ W0,
                       const float* __restrict__ biasY,
                       const float* __restrict__ ampv, const float* __restrict__ invv,
                       ushort_t* __restrict__ y, float* __restrict__ bnpart){
  __shared__ __align__(16) ushort_t Als[128][88];
  __shared__ __align__(16) ushort_t Bls[128][88];
  __shared__ float s_part[8][128];
  __shared__ float q_part[8][128];
  __shared__ float amp_s[128];
  __shared__ float inv_s[128];
  const int tid = threadIdx.x;
  const int m0 = blockIdx.x*128;
  const int w = tid >> 6, lane = tid & 63;
  const int wm = (w & 1)*64, wn = (w >> 1)*64;
  const int quad = lane >> 4, l15 = lane & 15;
  if(tid < 128){
    int rr = min(m0 + tid, NN-1);
    amp_s[tid] = ampv[rr];
    inv_s[tid] = invv[rr];
  }
  floatx4 accY[4][4] = {};

  for(int p=0; p<3; p++){
    floatx4 accP[4][4] = {};
    floatx4 (*tgt)[4] = (p==0) ? accY : accP;
    const ushort_t* Wp = Wcat + (size_t)p*128*512;
    for(int k0=0; k0<512; k0+=64){
      #pragma unroll
      for(int i=0;i<4;i++){
        int c = tid + 256*i;
        int row = c >> 3, kc = (c & 7)*8;
        uint4 va = make_uint4(0u,0u,0u,0u);
        int gr = m0 + row;
        if(gr < NN) va = *(const uint4*)(aggb + (size_t)gr*512 + k0 + kc);
        *(uint4*)(&Als[row][kc]) = va;
        uint4 vb = *(const uint4*)(Wp + (size_t)row*512 + k0 + kc);
        *(uint4*)(&Bls[row][kc]) = vb;
      }
      __syncthreads();
      #pragma unroll
      for(int ks=0; ks<64; ks+=32){
        bf16x8 a[4], b[4];
        #pragma unroll
        for(int i=0;i<4;i++) a[i] = *(const bf16x8*)(&Als[wm+16*i+l15][ks+quad*8]);
        #pragma unroll
        for(int j=0;j<4;j++) b[j] = *(const bf16x8*)(&Bls[wn+16*j+l15][ks+quad*8]);
        #pragma unroll
        for(int i=0;i<4;i++)
          #pragma unroll
          for(int j=0;j<4;j++)
            tgt[i][j] = __builtin_amdgcn_mfma_f32_16x16x32_bf16(a[i], b[j], tgt[i][j], 0, 0, 0);
      }
      __syncthreads();
    }
    if(p > 0){
      const float* cs = (p==1) ? amp_s : inv_s;
      #pragma unroll
      for(int i=0;i<4;i++)
        #pragma unroll
        for(int r=0;r<4;r++){
          float coef = cs[wm + 16*i + quad*4 + r];
          #pragma unroll
          for(int j=0;j<4;j++) accY[i][j][r] += coef*accP[i][j][r];
        }
    }
  }

  // + h @ W0f  (K=128)
  for(int k0=0; k0<128; k0+=64){
    #pragma unroll
    for(int i=0;i<4;i++){
      int c = tid + 256*i;
      int row = c >> 3, kc = (c & 7)*8;
      uint4 va = make_uint4(0u,0u,0u,0u);
      int gr = m0 + row;
      if(gr < NN) va = *(const uint4*)(h + (size_t)gr*128 + k0 + kc);
      *(uint4*)(&Als[row][kc]) = va;
      uint4 vb = *(const uint4*)(W0 + (size_t)row*128 + k0 + kc);
      *(uint4*)(&Bls[row][kc]) = vb;
    }
    __syncthreads();
    #pragma unroll
    for(int ks=0; ks<64; ks+=32){
      bf16x8 a[4], b[4];
      #pragma unroll
      for(int i=0;i<4;i++) a[i] = *(const bf16x8*)(&Als[wm+16*i+l15][ks+quad*8]);
      #pragma unroll
      for(int j=0;j<4;j++) b[j] = *(const bf16x8*)(&Bls[wn+16*j+l15][ks+quad*8]);
      #pragma unroll
      for(int i=0;i<4;i++)
        #pragma unroll
        for(int j=0;j<4;j++)
          accY[i][j] = __builtin_amdgcn_mfma_f32_16x16x32_bf16(a[i], b[j], accY[i][j], 0, 0, 0);
    }
    __syncthreads();
  }

  float s[4] = {0,0,0,0}, q[4] = {0,0,0,0};
  #pragma unroll
  for(int i=0;i<4;i++){
    #pragma unroll
    for(int r=0;r<4;r++){
      int grow = m0 + wm + 16*i + quad*4 + r;
      if(grow >= NN) continue;
      #pragma unroll
      for(int j=0;j<4;j++){
        int gcol = wn + 16*j + l15;
        float v = accY[i][j][r] + biasY[gcol];
        y[(size_t)grow*128 + gcol] = f2bf(v);
        s[j] += v; q[j] += v*v;
      }
    }
  }
  const int slot = (w & 1)*4 + quad;
  #pragma unroll
  for(int j=0;j<4;j++){
    s_part[slot][wn + 16*j + l15] = s[j];
    q_part[slot][wn + 16*j + l15] = q[j];
  }
  __syncthreads();
  if(tid < 128){
    float ss = 0.f, qq = 0.f;
    #pragma unroll
    for(int sl=0; sl<8; sl++){ ss += s_part[sl][tid]; qq += q_part[sl][tid]; }
    bnpart[(size_t)blockIdx.x*256 + tid]       = ss;
    bnpart[(size_t)blockIdx.x*256 + 128 + tid] = qq;
  }
}

// ---------------- PNA aggregation (Ah fp32, Bh bf16, ea bf16) ----------------
__launch_bounds__(128)
__global__ void k_agg(const int* __restrict__ rp, const int* __restrict__ src_csr,
                      const ushort_t* __restrict__ ea_csr, const float* __restrict__ Kf,
                      const float* __restrict__ Ah, const ushort_t* __restrict__ Bh,
                      ushort_t* __restrict__ agg, float* __restrict__ ampv,
                      float* __restrict__ invv){
  const int n = blockIdx.x, c = threadIdx.x;
  const int s0 = rp[n], e0 = rp[n+1];
  const int deg = e0 - s0;
  float kcol[16];
  #pragma unroll
  for(int k=0;k<16;k++) kcol[k] = Kf[k*128+c];
  const float base = Ah[(size_t)n*128 + c] + Kf[16*128+c];
  float sum=0.f, sq=0.f, mn=INFINITY, mx=-INFINITY;
  __shared__ float ea_s[16][16];
  __shared__ int src_s[16];
  for(int j0=s0; j0<e0; j0+=16){
    int cnt = min(16, e0-j0);
    __syncthreads();
    int ee = c>>4, kk = c&15;
    if(ee < cnt)   ea_s[ee][kk]   = bfu(ea_csr[(size_t)(j0+ee)*16+kk]);
    if(ee+8 < cnt) ea_s[ee+8][kk] = bfu(ea_csr[(size_t)(j0+ee+8)*16+kk]);
    if(c < cnt) src_s[c] = src_csr[j0+c];
    __syncthreads();
    for(int e=0;e<cnt;e++){
      float m = base + bfu(Bh[(size_t)src_s[e]*128 + c]);
      #pragma unroll
      for(int k=0;k<16;k++) m += ea_s[e][k]*kcol[k];
      sum += m; sq += m*m; mn = fminf(mn,m); mx = fmaxf(mx,m);
    }
  }
  float degc = (float)(deg>0?deg:1);
  float mean = sum/degc;
  float var  = fmaxf(sq/degc - mean*mean, 0.f);
  float sd = sqrtf(var + EPS_STD);
  if(deg==0){ mn=0.f; mx=0.f; }
  ushort_t* o = agg + (size_t)n*512;
  o[c]     = f2bf(mean);
  o[128+c] = f2bf(mn);
  o[256+c] = f2bf(mx);
  o[384+c] = f2bf(sd);
  if(c==0){
    float amp = logf(degc+1.f)/AVG_LOG;
    ampv[n] = amp; invv[n] = 1.f/amp;
  }
}

// ---------------- batchnorm ----------------
__global__ void k_bn_fin(const float* __restrict__ bnpart, int nb,
                         const float* __restrict__ gamma, const float* __restrict__ beta,
                         float* __restrict__ scale, float* __restrict__ shift){
  int c = threadIdx.x;
  float s0=0.f,s1=0.f,s2=0.f,s3=0.f, q0=0.f,q1=0.f,q2=0.f,q3=0.f;
  int b = 0;
  for(; b+3<nb; b+=4){
    s0 += bnpart[(size_t)(b+0)*256 + c];       q0 += bnpart[(size_t)(b+0)*256 + 128 + c];
    s1 += bnpart[(size_t)(b+1)*256 + c];       q1 += bnpart[(size_t)(b+1)*256 + 128 + c];
    s2 += bnpart[(size_t)(b+2)*256 + c];       q2 += bnpart[(size_t)(b+2)*256 + 128 + c];
    s3 += bnpart[(size_t)(b+3)*256 + c];       q3 += bnpart[(size_t)(b+3)*256 + 128 + c];
  }
  for(; b<nb; b++){ s0 += bnpart[(size_t)b*256 + c]; q0 += bnpart[(size_t)b*256 + 128 + c]; }
  float s = (s0+s1)+(s2+s3), q = (q0+q1)+(q2+q3);
  float mu  = s*(1.f/NN);
  float var = fmaxf(q*(1.f/NN) - mu*mu, 0.f);
  float inv = 1.f/sqrtf(var + EPS_BN);
  float sc = gamma[c]*inv;
  scale[c] = sc;
  shift[c] = beta[c] - mu*sc;
}

__global__ void k_bn_relu(const ushort_t* __restrict__ y, const float* __restrict__ scale,
                          const float* __restrict__ shift, ushort_t* __restrict__ h){
  int i = blockIdx.x*256 + threadIdx.x;
  if(i >= NN*128) return;
  int c = i & 127;
  float v = fmaxf(bfu(y[i])*scale[c] + shift[c], 0.f);
  h[i] = f2bf(v);
}

// ---------------- pooling (deterministic, chunked) + head ----------------
__device__ __forceinline__ int lbound(const int* a, int n, int v){
  int lo = 0, hi = n;
  while(lo < hi){ int mid = (lo+hi) >> 1; if(a[mid] < v) lo = mid+1; else hi = mid; }
  return lo;
}

__launch_bounds__(128)
__global__ void k_pool1(const ushort_t* __restrict__ h, const int* __restrict__ batch,
                        float* __restrict__ gpart){
  int b = blockIdx.x, ch = blockIdx.y, c = threadIdx.x;
  int lo = lbound(batch, NN, b), hi = lbound(batch, NN, b+1);
  int len = hi - lo;
  int per = (len + 7) >> 3;
  int r0 = min(lo + ch*per, hi);
  int r1 = min(r0 + per, hi);
  float acc = 0.f;
  for(int r=r0;r<r1;r++) acc += bfu(h[(size_t)r*128+c]);
  gpart[((size_t)b*8 + ch)*128 + c] = acc;
}

__global__ void k_pool2(const float* __restrict__ gpart, float* __restrict__ g){
  int b = blockIdx.x, c = threadIdx.x;
  float acc = 0.f;
  #pragma unroll
  for(int ch=0; ch<8; ch++) acc += gpart[((size_t)b*8 + ch)*128 + c];
  g[(size_t)b*128 + c] = acc;
}

__launch_bounds__(64)
__global__ void k_head(const float* __restrict__ g, const float* __restrict__ W1,
                       const float* __restrict__ b1, const float* __restrict__ W2,
                       const float* __restrict__ b2, void* __restrict__ out,
                       const int* __restrict__ flag){
  __shared__ float gs[128];
  __shared__ float zs[64];
  int r = blockIdx.x, tid = threadIdx.x;
  gs[tid] = g[r*128 + tid];
  gs[tid+64] = g[r*128 + tid + 64];
  __syncthreads();
  float a = b1[tid];
  for(int k=0;k<128;k++) a += gs[k]*W1[k*64+tid];
  zs[tid] = fmaxf(a, 0.f);
  __syncthreads();
  if(tid < NOUT){
    float o = b2[tid];
    for(int k=0;k<64;k++) o += zs[k]*W2[k*12+tid];
    if(*flag) ((ushort_t*)out)[r*NOUT + tid] = f2bf(o);
    else      ((float*)out)[r*NOUT + tid] = o;
  }
}

// ---------------- host ----------------
extern "C" void kernel_launch(void* const* d_in, const int* in_sizes, int n_in,
                              void* d_out, int out_size, void* d_ws, size_t ws_size,
                              hipStream_t stream){
  const void* x_raw = d_in[0];
  const void* ea_raw;
  const int*  eidx;
  const int*  batch;
  if(in_sizes[1] == 2*NE){           // signature order
    eidx   = (const int*)d_in[1];
    batch  = (const int*)d_in[2];
    ea_raw = d_in[3];
  } else {                           // dict order
    ea_raw = d_in[1];
    eidx   = (const int*)d_in[2];
    batch  = (const int*)d_in[3];
  }
  const void* nembW_r = d_in[4];
  const void* nembB_r = d_in[5];
  const void* eembW_r = d_in[6];
  const void* eembB_r = d_in[7];
  const void* encW_r  = d_in[8];
  const void* encB_r  = d_in[9];
  const void* preW_r  = d_in[10];
  const void* preB_r  = d_in[11];
  const void* postW_r = d_in[12];
  const void* postB_r = d_in[13];
  const void* linW_r  = d_in[14];
  const void* linB_r  = d_in[15];
  const void* bnG_r   = d_in[16];
  const void* bnB_r   = d_in[17];
  const void* h1W_r   = d_in[18];
  const void* h1B_r   = d_in[19];
  const void* h2W_r   = d_in[20];
  const void* h2B_r   = d_in[21];

  char* p = (char*)d_ws;
  auto alloc = [&](size_t bytes)->void*{
    void* r = (void*)p; p += (bytes + 255) & ~(size_t)255; return r;
  };
  int*      dtflag  = (int*)     alloc(sizeof(int)*16);
  int*      deg     = (int*)     alloc(sizeof(int)*NN);
  int*      fill    = (int*)     alloc(sizeof(int)*NN);
  int*      rp      = (int*)     alloc(sizeof(int)*(NN+1));
  int*      bsum    = (int*)     alloc(sizeof(int)*64);
  int*      boff    = (int*)     alloc(sizeof(int)*64);
  int*      src_csr = (int*)     alloc(sizeof(int)*NE);
  int*      eix_csr = (int*)     alloc(sizeof(int)*NE);
  ushort_t* ea_csr  = (ushort_t*)alloc(sizeof(ushort_t)*(size_t)NE*16);
  ushort_t* xbf     = (ushort_t*)alloc(sizeof(ushort_t)*(size_t)NN*64);
  ushort_t* h       = (ushort_t*)alloc(sizeof(ushort_t)*(size_t)NN*128);
  ushort_t* aggb    = (ushort_t*)alloc(sizeof(ushort_t)*(size_t)NN*512);
  float*    Ah      = (float*)   alloc(sizeof(float)*(size_t)NN*128);
  ushort_t* Bh      = (ushort_t*)alloc(sizeof(ushort_t)*(size_t)NN*128);
  ushort_t* y       = (ushort_t*)alloc(sizeof(ushort_t)*(size_t)NN*128);
  float*    ampv    = (float*)   alloc(sizeof(float)*(NN+256));
  float*    invv    = (float*)   alloc(sizeof(float)*(NN+256));
  float*    Kf      = (float*)   alloc(sizeof(float)*4*17*128);
  float*    bnpart  = (float*)   alloc(sizeof(float)*(size_t)MB_GRID*256);
  float*    bnscale = (float*)   alloc(sizeof(float)*128);
  float*    bnshift = (float*)   alloc(sizeof(float)*128);
  float*    gpart   = (float*)   alloc(sizeof(float)*32*8*128);
  float*    g       = (float*)   alloc(sizeof(float)*32*128);
  float*    biasY   = (float*)   alloc(sizeof(float)*4*128);
  ushort_t* WembT   = (ushort_t*)alloc(sizeof(ushort_t)*128*64);
  ushort_t* P12T    = (ushort_t*)alloc(sizeof(ushort_t)*4*256*128);
  ushort_t* WcatFT  = (ushort_t*)alloc(sizeof(ushort_t)*(size_t)4*384*512);
  ushort_t* W0FT    = (ushort_t*)alloc(sizeof(ushort_t)*4*128*128);
  float* nembW = (float*)alloc(sizeof(float)*64*128);
  float* nembB = (float*)alloc(sizeof(float)*128);
  float* eembW = (float*)alloc(sizeof(float)*16*128);
  float* eembB = (float*)alloc(sizeof(float)*128);
  float* encW  = (float*)alloc(sizeof(float)*4*128*128);
  float* encB  = (float*)alloc(sizeof(float)*4*128);
  float* preW  = (float*)alloc(sizeof(float)*4*384*128);
  float* preB  = (float*)alloc(sizeof(float)*4*128);
  float* postW = (float*)alloc(sizeof(float)*(size_t)4*1664*128);
  float* postB = (float*)alloc(sizeof(float)*4*128);
  float* linW  = (float*)alloc(sizeof(float)*4*128*128);
  float* linB  = (float*)alloc(sizeof(float)*4*128);
  float* bnG   = (float*)alloc(sizeof(float)*4*128);
  float* bnB   = (float*)alloc(sizeof(float)*4*128);
  float* h1W   = (float*)alloc(sizeof(float)*128*64);
  float* h1B   = (float*)alloc(sizeof(float)*64);
  float* h2W   = (float*)alloc(sizeof(float)*64*12);
  float* h2B   = (float*)alloc(sizeof(float)*12);

  CvtArgs ca;
  ca.flag = dtflag;
  int ji = 0;
  auto job = [&](const void* s, float* d, int n){ ca.j[ji].s=s; ca.j[ji].d=d; ca.j[ji].n=n; ji++; };
  job(nembW_r, nembW, 64*128);
  job(nembB_r, nembB, 128);
  job(eembW_r, eembW, 16*128);
  job(eembB_r, eembB, 128);
  job(encW_r,  encW,  4*128*128);
  job(encB_r,  encB,  4*128);
  job(preW_r,  preW,  4*384*128);
  job(preB_r,  preB,  4*128);
  job(postW_r, postW, 4*1664*128);
  job(postB_r, postB, 4*128);
  job(linW_r,  linW,  4*128*128);
  job(linB_r,  linB,  4*128);
  job(bnG_r,   bnG,   4*128);
  job(bnB_r,   bnB,   4*128);
  job(h1W_r,   h1W,   128*64);
  job(h1B_r,   h1B,   64);
  job(h2W_r,   h2W,   64*12);
  job(h2B_r,   h2B,   12);

  TrArgs ta;
  int ti = 0;
  auto tj = [&](const float* s, ushort_t* d, int K, int N){ ta.j[ti].s=s; ta.j[ti].d=d; ta.j[ti].K=K; ta.j[ti].N=N; ti++; };
  tj(nembW, WembT, 64, 128);
  for(int l=0;l<4;l++){
    const float* pw = preW + (size_t)l*384*128;
    tj(pw,           P12T + (size_t)l*256*128,           128, 128);
    tj(pw + 128*128, P12T + (size_t)l*256*128 + 128*128, 128, 128);
  }

  FoldArgs fa;
  int fi = 0;
  for(int l=0;l<4;l++){
    const float* po = postW + (size_t)l*1664*128;
    const float* L  = linW + (size_t)l*128*128;
    for(int b=0;b<3;b++){
      fa.j[fi].s1 = po + (size_t)(128 + b*512)*128;
      fa.j[fi].s2 = L;
      fa.j[fi].d  = WcatFT + (size_t)l*384*512 + (size_t)b*128*512;
      fa.j[fi].Kd = 512;
      fi++;
    }
    fa.j[fi].s1 = po;
    fa.j[fi].s2 = L;
    fa.j[fi].d  = W0FT + (size_t)l*128*128;
    fa.j[fi].Kd = 128;
    fi++;
  }

  const int* esrc = eidx;
  const int* edst = eidx + NE;

  hipMemsetAsync(deg, 0, sizeof(int)*NN, stream);
  hipMemsetAsync(fill, 0, sizeof(int)*NN, stream);

  k_detect<<<1, 256, 0, stream>>>((const ushort_t*)x_raw, dtflag);
  k_cvt<<<dim3(128, NJOBS), 256, 0, stream>>>(ca);
  k_xbf<<<(NN*64+255)/256, 256, 0, stream>>>(x_raw, xbf, dtflag);
  k_tr<<<dim3(4, NTR), 256, 0, stream>>>(ta);
  k_fold<<<dim3(8, NFOLD), 256, 0, stream>>>(fa);
  k_foldb<<<4, 128, 0, stream>>>(postB, linW, linB, biasY);
  k_prep_K<<<68, 128, 0, stream>>>(eembW, eembB, encW, encB, preW, preB, Kf);

  k_deg<<<(NE+255)/256, 256, 0, stream>>>(edst, deg);
  k_scan1<<<30, 1024, 0, stream>>>(deg, rp, bsum);
  k_scan2<<<1, 64, 0, stream>>>(bsum, boff, rp, 30);
  k_scan3<<<30, 1024, 0, stream>>>(rp, boff);
  k_scatter<<<(NE+255)/256, 256, 0, stream>>>(edst, rp, fill, eix_csr);
  k_srt<<<(NN+63)/64, 64, 0, stream>>>(rp, eix_csr);
  k_gather_ea<<<(NE+127)/128, 128, 0, stream>>>(eix_csr, esrc, ea_raw, ea_csr, src_csr, dtflag);

  // h = x @ Wemb + b  (bf16 out)
  k_mm<0,1><<<dim3(MB_GRID,1), 256, 0, stream>>>(xbf, WembT, h, nullptr, NN, 64, 128, nembB);

  for(int l=0; l<NLAYER; l++){
    // [Ah | Bh] = h @ [P1|P2]  (mixed fp32/bf16 out)
    k_mm<2,0><<<dim3(MB_GRID,2), 256, 0, stream>>>(h, P12T + (size_t)l*256*128, Ah, Bh,
                                                   NN, 128, 128, nullptr);
    k_agg<<<NN, 128, 0, stream>>>(rp, src_csr, ea_csr, Kf + (size_t)l*17*128,
                                  Ah, Bh, aggb, ampv, invv);
    // y = agg@WcatF (amp-combined) + h@W0f + biasY  (bf16 out + BN partials)
    k_post<<<MB_GRID, 256, 0, stream>>>(aggb, h, WcatFT + (size_t)l*384*512,
                                        W0FT + (size_t)l*128*128, biasY + l*128,
                                        ampv, invv, y, bnpart);
    k_bn_fin<<<1, 128, 0, stream>>>(bnpart, MB_GRID, bnG + l*128, bnB + l*128,
                                    bnscale, bnshift);
    k_bn_relu<<<(NN*128+255)/256, 256, 0, stream>>>(y, bnscale, bnshift, h);
  }

  k_pool1<<<dim3(NGR,8), 128, 0, stream>>>(h, batch, gpart);
  k_pool2<<<NGR, 128, 0, stream>>>(gpart, g);
  k_head<<<NGR, 64, 0, stream>>>(g, h1W, h1B, h2W, h2B, d_out, dtflag);
}